// Round 1
// 458.393 us; speedup vs baseline: 1.0770x; 1.0770x over previous
//
#include <hip/hip_runtime.h>
#include <hip/hip_fp16.h>
#include <math.h>

#define N_NODES   100000
#define N_EDGES   1600000
#define N_FEAT    64
#define HIDDEN    64
#define BIOPRINT  2048
#define N_GRAPHS  1024

#define SCAN_BLK  1024
#define N_SCAN_BLOCKS ((N_NODES + SCAN_BLK - 1) / SCAN_BLK)   // 98
#define XCD_SLICE 12500                                        // nodes per XCD slice
#define FILL_BLOCKS 2000                                       // 250 blocks x 8 slices
#define SLICE_THREADS (250 * 256)                              // threads per slice
#define MM_GRID (N_NODES / 4)                                  // 25000
#define N_E4 (N_EDGES / 4)                                     // 400000
#define DEG_BLOCKS ((N_E4 + 255) / 256)                        // 1563

__device__ __forceinline__ __half2 shx_h2(__half2 v, int m) {
    int x = __shfl_xor(*(int*)&v, m);
    return *(__half2*)&x;
}

// ---------------- degree + edge rank: atomicAdd's return value IS the rank ----------------
// rank[e] = position of edge e within its dst row; makes the CSR fill atomic-free.

__global__ __launch_bounds__(256) void k_deg(const int* __restrict__ dst,
                                             int* __restrict__ deg,
                                             int* __restrict__ rank) {
    int tid = blockIdx.x * blockDim.x + threadIdx.x;
    if (tid >= N_E4) return;
    int4 d4 = ((const int4*)dst)[tid];
    int4 r4;
    r4.x = atomicAdd(&deg[d4.x], 1);
    r4.y = atomicAdd(&deg[d4.y], 1);
    r4.z = atomicAdd(&deg[d4.z], 1);
    r4.w = atomicAdd(&deg[d4.w], 1);
    ((int4*)rank)[tid] = r4;   // coalesced full-line store
}

// ---------------- CSR build: scan1 (+dinv), scan3 (+inline bsum scan, +gstart) ----------------

__global__ __launch_bounds__(SCAN_BLK) void k_scan1(
        const int* __restrict__ deg, int* __restrict__ incl,
        int* __restrict__ bsum, float* __restrict__ dinv, int n) {
    __shared__ int tmp[SCAN_BLK];
    int t = threadIdx.x;
    int i = blockIdx.x * SCAN_BLK + t;
    int v = (i < n) ? deg[i] : 0;
    if (i < n) dinv[i] = rsqrtf((float)v + 1.0f);
    tmp[t] = v;
    __syncthreads();
    for (int off = 1; off < SCAN_BLK; off <<= 1) {
        int u = (t >= off) ? tmp[t - off] : 0;
        __syncthreads();
        tmp[t] += u;
        __syncthreads();
    }
    if (i < n) incl[i] = tmp[t];
    if (t == SCAN_BLK - 1) bsum[blockIdx.x] = tmp[t];
}

__global__ __launch_bounds__(SCAN_BLK) void k_scan3(
        int* __restrict__ rowptr, const int* __restrict__ deg,
        const int* __restrict__ bsum,
        const int* __restrict__ batch, int* __restrict__ gstart, int n) {
    int t = threadIdx.x;
    int bid = blockIdx.x;
    if (bid >= N_SCAN_BLOCKS) {
        int g = (bid - N_SCAN_BLOCKS) * SCAN_BLK + t;
        if (g > N_GRAPHS) return;
        if (g == N_GRAPHS) { gstart[g] = N_NODES; return; }
        int lo = 0, hi = N_NODES;
        while (lo < hi) { int mid = (lo + hi) >> 1; if (batch[mid] < g) lo = mid + 1; else hi = mid; }
        gstart[g] = lo;
        return;
    }
    __shared__ int sb[128];
    if (t < 128) sb[t] = (t < N_SCAN_BLOCKS) ? bsum[t] : 0;
    __syncthreads();
    for (int off = 1; off < 128; off <<= 1) {
        int u = (t >= off && t < 128) ? sb[t - off] : 0;
        __syncthreads();
        if (t < 128) sb[t] += u;
        __syncthreads();
    }
    int base = (bid == 0) ? 0 : sb[bid - 1];
    int i = bid * SCAN_BLK + t;
    if (i < n) rowptr[i] = rowptr[i] - deg[i] + base;
    if (i == 0) rowptr[n] = N_EDGES;
}

// ---------------- fat kernel: XCD-sliced atomic-free fill + layer-1 matmul ----------------
// Blocks [0, FILL_BLOCKS): fill slice p=bid&7 (dst in [12500p,12500(p+1))).
//   No atomics: col[rowptr[d] + rank[e]] = src[e]. int4 dst scan, fully pipelineable.
//   Slicing kept so scattered col stores stay XCD-L2-local (perf only; positions are
//   globally unique so correctness no longer depends on block->XCD mapping).
// Blocks [FILL_BLOCKS, FILL_BLOCKS+MM_GRID): hw1' = fp16[(x @ W1) * dinv].
__global__ __launch_bounds__(256) void k_fillmm(
        const int* __restrict__ src, const int* __restrict__ dst,
        const int* __restrict__ rank, const int* __restrict__ rowptr,
        int* __restrict__ col,
        const float* __restrict__ h, const float* __restrict__ W,
        const float* __restrict__ dinv, __half* __restrict__ hw) {
    int bid = blockIdx.x;
    if (bid < FILL_BLOCKS) {
        int p = bid & 7;
        int lo = p * XCD_SLICE, hi = lo + XCD_SLICE;
        const int4* dst4 = (const int4*)dst;
        for (int i4 = (bid >> 3) * 256 + threadIdx.x; i4 < N_E4; i4 += SLICE_THREADS) {
            int4 d4 = dst4[i4];
            int e = i4 * 4;
            if (d4.x >= lo && d4.x < hi)
                col[rowptr[d4.x] + rank[e + 0]] = src[e + 0];
            if (d4.y >= lo && d4.y < hi)
                col[rowptr[d4.y] + rank[e + 1]] = src[e + 1];
            if (d4.z >= lo && d4.z < hi)
                col[rowptr[d4.z] + rank[e + 2]] = src[e + 2];
            if (d4.w >= lo && d4.w < hi)
                col[rowptr[d4.w] + rank[e + 3]] = src[e + 3];
        }
        return;
    }
    __shared__ float sW[64 * 64];
    __shared__ float sH[4 * 64];
    int t = threadIdx.x;
    const float4* W4 = (const float4*)W;
    float4* sW4 = (float4*)sW;
    for (int i = t; i < 1024; i += 256) sW4[i] = W4[i];
    int row0 = (bid - FILL_BLOCKS) * 4;
    int r = t >> 6, j = t & 63;
    sH[r * 64 + j] = h[(row0 + r) * 64 + j];
    __syncthreads();
    int i = row0 + r;
    float sum = 0.0f;
#pragma unroll
    for (int k = 0; k < 64; ++k) sum = fmaf(sH[r * 64 + k], sW[k * 64 + j], sum);
    hw[i * 64 + j] = __float2half_rn(sum * dinv[i]);
}

// ---------------- gather core: 4 nodes per wave, 2 slots/node, 4 loads in flight ----------------
__device__ __forceinline__ void gather2x4(
        const int* __restrict__ col, const uint4* __restrict__ hv,
        int rs, int re, int slot, int sub, float f[8]) {
    __half2 a0 = __float2half2_rn(0.f), a1 = a0, a2 = a0, a3 = a0;
    __half2 c0 = a0, c1 = a0, c2 = a0, c3 = a0;
    int e = rs;
    for (; e + 8 <= re; e += 8) {
        int s0 = __builtin_nontemporal_load(&col[e + slot]);
        int s1 = __builtin_nontemporal_load(&col[e + 2 + slot]);
        int s2 = __builtin_nontemporal_load(&col[e + 4 + slot]);
        int s3 = __builtin_nontemporal_load(&col[e + 6 + slot]);
        uint4 u0 = hv[(size_t)s0 * 8 + sub];
        uint4 u1 = hv[(size_t)s1 * 8 + sub];
        uint4 u2 = hv[(size_t)s2 * 8 + sub];
        uint4 u3 = hv[(size_t)s3 * 8 + sub];
        a0 = __hadd2(a0, *(__half2*)&u0.x); a1 = __hadd2(a1, *(__half2*)&u0.y);
        a2 = __hadd2(a2, *(__half2*)&u0.z); a3 = __hadd2(a3, *(__half2*)&u0.w);
        c0 = __hadd2(c0, *(__half2*)&u1.x); c1 = __hadd2(c1, *(__half2*)&u1.y);
        c2 = __hadd2(c2, *(__half2*)&u1.z); c3 = __hadd2(c3, *(__half2*)&u1.w);
        a0 = __hadd2(a0, *(__half2*)&u2.x); a1 = __hadd2(a1, *(__half2*)&u2.y);
        a2 = __hadd2(a2, *(__half2*)&u2.z); a3 = __hadd2(a3, *(__half2*)&u2.w);
        c0 = __hadd2(c0, *(__half2*)&u3.x); c1 = __hadd2(c1, *(__half2*)&u3.y);
        c2 = __hadd2(c2, *(__half2*)&u3.z); c3 = __hadd2(c3, *(__half2*)&u3.w);
    }
    for (; e + slot < re; e += 2) {
        int s0 = col[e + slot];
        uint4 u0 = hv[(size_t)s0 * 8 + sub];
        a0 = __hadd2(a0, *(__half2*)&u0.x); a1 = __hadd2(a1, *(__half2*)&u0.y);
        a2 = __hadd2(a2, *(__half2*)&u0.z); a3 = __hadd2(a3, *(__half2*)&u0.w);
    }
    a0 = __hadd2(a0, c0); a1 = __hadd2(a1, c1);
    a2 = __hadd2(a2, c2); a3 = __hadd2(a3, c3);
    a0 = __hadd2(a0, shx_h2(a0, 8));
    a1 = __hadd2(a1, shx_h2(a1, 8));
    a2 = __hadd2(a2, shx_h2(a2, 8));
    a3 = __hadd2(a3, shx_h2(a3, 8));
    float2 f0 = __half22float2(a0), f1 = __half22float2(a1);
    float2 f2 = __half22float2(a2), f3 = __half22float2(a3);
    f[0] = f0.x; f[1] = f0.y; f[2] = f1.x; f[3] = f1.y;
    f[4] = f2.x; f[5] = f2.y; f[6] = f3.x; f[7] = f3.y;
}

// ---------------- fused gather(4 nodes/wave) + relu + LDS matmul ----------------
__global__ __launch_bounds__(256) void k_gmm(
        const int* __restrict__ rowptr, const int* __restrict__ col,
        const float* __restrict__ dinv, const float* __restrict__ b,
        const __half* __restrict__ hw_in, const float* __restrict__ W,
        __half* __restrict__ hw_out) {
    __shared__ float sW[64 * 64];
    __shared__ float sA[16 * 64];
    int t = threadIdx.x;
    const float4* W4 = (const float4*)W;
    float4* sW4 = (float4*)sW;
    for (int i = t; i < 1024; i += 256) sW4[i] = W4[i];
    __syncthreads();

    int wave = t >> 6, lane = t & 63;
    int quarter = lane >> 4, slot = (lane >> 3) & 1, sub = lane & 7;
    int i0 = blockIdx.x * 16 + wave * 4;
    int i = i0 + quarter;
    float di = dinv[i];
    int rs = rowptr[i], re = rowptr[i + 1];
    const uint4* hv = (const uint4*)hw_in;

    float f[8];
    gather2x4(col, hv, rs, re, slot, sub, f);

    uint4 us = hv[(size_t)i * 8 + sub];
    float2 s0 = __half22float2(*(__half2*)&us.x);
    float2 s1 = __half22float2(*(__half2*)&us.y);
    float2 s2 = __half22float2(*(__half2*)&us.z);
    float2 s3 = __half22float2(*(__half2*)&us.w);
    float sf[8] = {s0.x, s0.y, s1.x, s1.y, s2.x, s2.y, s3.x, s3.y};
    float4 ba = ((const float4*)b)[sub * 2];
    float4 bb = ((const float4*)b)[sub * 2 + 1];
    float bf[8] = {ba.x, ba.y, ba.z, ba.w, bb.x, bb.y, bb.z, bb.w};
    if (slot == 0) {
        float r[8];
#pragma unroll
        for (int k = 0; k < 8; ++k) r[k] = fmaxf(fmaf(di, f[k] + sf[k], bf[k]), 0.f);
        *(float4*)&sA[(wave * 4 + quarter) * 64 + sub * 8]     = make_float4(r[0], r[1], r[2], r[3]);
        *(float4*)&sA[(wave * 4 + quarter) * 64 + sub * 8 + 4] = make_float4(r[4], r[5], r[6], r[7]);
    }

#pragma unroll
    for (int h = 0; h < 4; ++h) {
        const float4* sA4 = (const float4*)&sA[(wave * 4 + h) * 64];
        float sum = 0.f;
#pragma unroll
        for (int k4 = 0; k4 < 16; ++k4) {
            float4 a4 = sA4[k4];
            sum = fmaf(a4.x, sW[(k4 * 4 + 0) * 64 + lane], sum);
            sum = fmaf(a4.y, sW[(k4 * 4 + 1) * 64 + lane], sum);
            sum = fmaf(a4.z, sW[(k4 * 4 + 2) * 64 + lane], sum);
            sum = fmaf(a4.w, sW[(k4 * 4 + 3) * 64 + lane], sum);
        }
        hw_out[(size_t)(i0 + h) * 64 + lane] = __float2half_rn(sum * dinv[i0 + h]);
    }
}

// ---------------- layer-3 gather (4 nodes/wave; fp16 conv out) ----------------
__global__ __launch_bounds__(256) void k_gather3(
        const int* __restrict__ rowptr, const int* __restrict__ col,
        const float* __restrict__ dinv, const float* __restrict__ b,
        const __half* __restrict__ hw_in, __half* __restrict__ conv) {
    int t = threadIdx.x;
    int wave = t >> 6, lane = t & 63;
    int quarter = lane >> 4, slot = (lane >> 3) & 1, sub = lane & 7;
    int i = blockIdx.x * 16 + wave * 4 + quarter;
    float di = dinv[i];
    int rs = rowptr[i], re = rowptr[i + 1];
    const uint4* hv = (const uint4*)hw_in;

    float f[8];
    gather2x4(col, hv, rs, re, slot, sub, f);

    if (slot == 0) {
        uint4 us = hv[(size_t)i * 8 + sub];
        float2 s0 = __half22float2(*(__half2*)&us.x);
        float2 s1 = __half22float2(*(__half2*)&us.y);
        float2 s2 = __half22float2(*(__half2*)&us.z);
        float2 s3 = __half22float2(*(__half2*)&us.w);
        float sf[8] = {s0.x, s0.y, s1.x, s1.y, s2.x, s2.y, s3.x, s3.y};
        float4 ba = ((const float4*)b)[sub * 2];
        float4 bb = ((const float4*)b)[sub * 2 + 1];
        float bf[8] = {ba.x, ba.y, ba.z, ba.w, bb.x, bb.y, bb.z, bb.w};
        uint4 o;
        __half2* oh = (__half2*)&o;
#pragma unroll
        for (int c = 0; c < 4; ++c) {
            float r0 = fmaf(di, f[2 * c] + sf[2 * c], bf[2 * c]);
            float r1 = fmaf(di, f[2 * c + 1] + sf[2 * c + 1], bf[2 * c + 1]);
            oh[c] = __halves2half2(__float2half_rn(r0), __float2half_rn(r1));
        }
        ((uint4*)conv)[(size_t)i * 8 + sub] = o;
    }
}

// ---------------- fused mean-pool + dense + softmax + threshold: 8 graphs/block ----------------
__global__ __launch_bounds__(256) void k_dense(
        const __half* __restrict__ conv, const int* __restrict__ gstart,
        const float* __restrict__ Wd, const float* __restrict__ bd,
        float* __restrict__ out) {
    __shared__ float sp[8][64];
    __shared__ float red[8][4];
    int t = threadIdx.x;
    int wave = t >> 6, lane = t & 63;
    int g0 = blockIdx.x * 8;
#pragma unroll
    for (int gg = 0; gg < 2; ++gg) {
        int g = wave * 2 + gg;
        int n0 = gstart[g0 + g], n1 = gstart[g0 + g + 1];
        float acc = 0.f;
        int i = n0;
        for (; i + 1 < n1; i += 2) {
            float v0 = __half2float(conv[(size_t)i * 64 + lane]);
            float v1 = __half2float(conv[(size_t)(i + 1) * 64 + lane]);
            acc += v0 + v1;
        }
        if (i < n1) acc += __half2float(conv[(size_t)i * 64 + lane]);
        int n = n1 - n0;
        sp[g][lane] = (n > 0) ? acc / (float)n : 0.f;
    }
    __syncthreads();

    float acc[8][8];
#pragma unroll
    for (int r = 0; r < 8; ++r) {
        float bv = bd[r * 256 + t];
#pragma unroll
        for (int g = 0; g < 8; ++g) acc[g][r] = bv;
    }
    for (int k = 0; k < 64; ++k) {
        float w[8];
#pragma unroll
        for (int r = 0; r < 8; ++r) w[r] = Wd[k * BIOPRINT + r * 256 + t];
#pragma unroll
        for (int g = 0; g < 8; ++g) {
            float h = sp[g][k];
#pragma unroll
            for (int r = 0; r < 8; ++r) acc[g][r] = fmaf(h, w[r], acc[g][r]);
        }
    }
    float gm[8];
#pragma unroll
    for (int g = 0; g < 8; ++g) {
        float m = acc[g][0];
#pragma unroll
        for (int r = 1; r < 8; ++r) m = fmaxf(m, acc[g][r]);
#pragma unroll
        for (int off = 32; off > 0; off >>= 1) m = fmaxf(m, __shfl_xor(m, off));
        if (lane == 0) red[g][wave] = m;
    }
    __syncthreads();
#pragma unroll
    for (int g = 0; g < 8; ++g)
        gm[g] = fmaxf(fmaxf(red[g][0], red[g][1]), fmaxf(red[g][2], red[g][3]));
    __syncthreads();
    float gs[8];
#pragma unroll
    for (int g = 0; g < 8; ++g) {
        float s = 0.f;
#pragma unroll
        for (int r = 0; r < 8; ++r) { acc[g][r] = expf(acc[g][r] - gm[g]); s += acc[g][r]; }
#pragma unroll
        for (int off = 32; off > 0; off >>= 1) s += __shfl_xor(s, off);
        if (lane == 0) red[g][wave] = s;
    }
    __syncthreads();
#pragma unroll
    for (int g = 0; g < 8; ++g)
        gs[g] = red[g][0] + red[g][1] + red[g][2] + red[g][3];
#pragma unroll
    for (int g = 0; g < 8; ++g)
#pragma unroll
        for (int r = 0; r < 8; ++r) {
            float p = acc[g][r] / gs[g];
            out[(size_t)(g0 + g) * BIOPRINT + r * 256 + t] = (p >= 0.5f) ? 1.0f : 0.0f;
        }
}

// ---------------- launch ----------------

extern "C" void kernel_launch(void* const* d_in, const int* in_sizes, int n_in,
                              void* d_out, int out_size, void* d_ws, size_t ws_size,
                              hipStream_t stream) {
    const float* x     = (const float*)d_in[0];
    const int*   ei    = (const int*)d_in[1];
    const int*   batch = (const int*)d_in[2];
    const float* W1 = (const float*)d_in[3];
    const float* b1 = (const float*)d_in[4];
    const float* W2 = (const float*)d_in[5];
    const float* b2 = (const float*)d_in[6];
    const float* W3 = (const float*)d_in[7];
    const float* b3 = (const float*)d_in[8];
    const float* Wd = (const float*)d_in[9];
    const float* bd = (const float*)d_in[10];
    float* out = (float*)d_out;

    const int* src = ei;
    const int* dst = ei + N_EDGES;

    char* ws = (char*)d_ws;
    size_t off = 0;
    auto alloc = [&](size_t bytes) {
        void* p = ws + off;
        off += (bytes + 255) & ~(size_t)255;
        return p;
    };
    int*    deg    = (int*)alloc(N_NODES * sizeof(int));
    float*  dinv   = (float*)alloc(N_NODES * sizeof(float));
    int*    rowptr = (int*)alloc((N_NODES + 1) * sizeof(int));
    int*    bsum   = (int*)alloc(128 * sizeof(int));
    int*    rank   = (int*)alloc((size_t)N_EDGES * sizeof(int));
    int*    gstart = (int*)alloc((N_GRAPHS + 1) * sizeof(int));
    int*    col    = (int*)alloc((size_t)N_EDGES * sizeof(int));
    __half* bufA   = (__half*)alloc((size_t)N_NODES * HIDDEN * sizeof(__half));
    __half* bufB   = (__half*)alloc((size_t)N_NODES * HIDDEN * sizeof(__half));
    __half* conv   = (__half*)alloc((size_t)N_NODES * HIDDEN * sizeof(__half));

    hipMemsetAsync(deg, 0, N_NODES * sizeof(int), stream);

    k_deg<<<DEG_BLOCKS, 256, 0, stream>>>(dst, deg, rank);
    k_scan1<<<N_SCAN_BLOCKS, SCAN_BLK, 0, stream>>>(deg, rowptr, bsum, dinv, N_NODES);
    k_scan3<<<N_SCAN_BLOCKS + 2, SCAN_BLK, 0, stream>>>(rowptr, deg, bsum,
                                                        batch, gstart, N_NODES);
    // atomic-free fill + layer-1 matmul fused (independent work, co-scheduled)
    k_fillmm<<<FILL_BLOCKS + MM_GRID, 256, 0, stream>>>(src, dst, rank, rowptr, col,
                                                        x, W1, dinv, bufA);

    const int g16_grid = N_NODES / 16;         // 6250 (16 nodes/block)
    k_gmm<<<g16_grid, 256, 0, stream>>>(rowptr, col, dinv, b1, bufA, W2, bufB);
    k_gmm<<<g16_grid, 256, 0, stream>>>(rowptr, col, dinv, b2, bufB, W3, bufA);
    k_gather3<<<g16_grid, 256, 0, stream>>>(rowptr, col, dinv, b3, bufA, conv);
    k_dense<<<N_GRAPHS / 8, 256, 0, stream>>>(conv, gstart, Wd, bd, out);
}

// Round 2
// 442.521 us; speedup vs baseline: 1.1156x; 1.0359x over previous
//
#include <hip/hip_runtime.h>
#include <hip/hip_fp16.h>
#include <math.h>

#define N_NODES   100000
#define N_EDGES   1600000
#define N_FEAT    64
#define HIDDEN    64
#define BIOPRINT  2048
#define N_GRAPHS  1024

#define SENTINEL  N_NODES                                      // zero feature row
#define COL_CAP   (N_EDGES + 8 * N_NODES)                      // padded col capacity

#define SCAN_BLK  1024
#define N_SCAN_BLOCKS ((N_NODES + SCAN_BLK - 1) / SCAN_BLK)   // 98
#define XCD_SLICE 12500                                        // nodes per XCD slice
#define FILL_BLOCKS 2000                                       // 250 blocks x 8 slices
#define SLICE_THREADS (250 * 256)                              // threads per slice
#define MM_GRID (N_NODES / 4)                                  // 25000
#define N_E4 (N_EDGES / 4)                                     // 400000
#define DEG_BLOCKS ((N_E4 + 255) / 256)                        // 1563

__device__ __forceinline__ __half2 shx_h2(__half2 v, int m) {
    int x = __shfl_xor(*(int*)&v, m);
    return *(__half2*)&x;
}

// ---------------- degree + edge rank: atomicAdd's return value IS the rank ----------------

__global__ __launch_bounds__(256) void k_deg(const int* __restrict__ dst,
                                             int* __restrict__ deg,
                                             int* __restrict__ rank) {
    int tid = blockIdx.x * blockDim.x + threadIdx.x;
    if (tid >= N_E4) return;
    int4 d4 = ((const int4*)dst)[tid];
    int4 r4;
    r4.x = atomicAdd(&deg[d4.x], 1);
    r4.y = atomicAdd(&deg[d4.y], 1);
    r4.z = atomicAdd(&deg[d4.z], 1);
    r4.w = atomicAdd(&deg[d4.w], 1);
    ((int4*)rank)[tid] = r4;   // coalesced full-line store
}

// ---------------- CSR build over PADDED degrees (rows padded to multiple of 8) ----------------

__global__ __launch_bounds__(SCAN_BLK) void k_scan1(
        const int* __restrict__ deg, int* __restrict__ incl,
        int* __restrict__ bsum, float* __restrict__ dinv, int n) {
    __shared__ int tmp[SCAN_BLK];
    int t = threadIdx.x;
    int i = blockIdx.x * SCAN_BLK + t;
    int v = (i < n) ? deg[i] : 0;
    if (i < n) dinv[i] = rsqrtf((float)v + 1.0f);
    int vp = (v + 7) & ~7;          // padded degree
    tmp[t] = vp;
    __syncthreads();
    for (int off = 1; off < SCAN_BLK; off <<= 1) {
        int u = (t >= off) ? tmp[t - off] : 0;
        __syncthreads();
        tmp[t] += u;
        __syncthreads();
    }
    if (i < n) incl[i] = tmp[t];
    if (t == SCAN_BLK - 1) bsum[blockIdx.x] = tmp[t];
}

__global__ __launch_bounds__(SCAN_BLK) void k_scan3(
        int* __restrict__ rowptr, const int* __restrict__ deg,
        const int* __restrict__ bsum, int* __restrict__ col,
        const int* __restrict__ batch, int* __restrict__ gstart, int n) {
    int t = threadIdx.x;
    int bid = blockIdx.x;
    if (bid >= N_SCAN_BLOCKS) {
        int g = (bid - N_SCAN_BLOCKS) * SCAN_BLK + t;
        if (g > N_GRAPHS) return;
        if (g == N_GRAPHS) { gstart[g] = N_NODES; return; }
        int lo = 0, hi = N_NODES;
        while (lo < hi) { int mid = (lo + hi) >> 1; if (batch[mid] < g) lo = mid + 1; else hi = mid; }
        gstart[g] = lo;
        return;
    }
    __shared__ int sb[128];
    if (t < 128) sb[t] = (t < N_SCAN_BLOCKS) ? bsum[t] : 0;
    __syncthreads();
    for (int off = 1; off < 128; off <<= 1) {
        int u = (t >= off && t < 128) ? sb[t - off] : 0;
        __syncthreads();
        if (t < 128) sb[t] += u;
        __syncthreads();
    }
    int base = (bid == 0) ? 0 : sb[bid - 1];
    int i = bid * SCAN_BLK + t;
    if (i < n) {
        int v = deg[i];
        int vp = (v + 7) & ~7;
        int ex = rowptr[i] - vp + base;   // exclusive padded start
        rowptr[i] = ex;
        // sentinel-fill the pad region [ex+v, ex+vp): nearly-sequential across threads
        for (int j = v; j < vp; ++j) col[ex + j] = SENTINEL;
    }
    if (bid == 0 && t == 0) rowptr[n] = sb[N_SCAN_BLOCKS - 1];  // padded total
}

// ---------------- fat kernel: XCD-sliced atomic-free fill + layer-1 matmul ----------------
// Blocks [0, FILL_BLOCKS): fill slice p=bid&7 (dst in [12500p,12500(p+1))).
//   No atomics: col[rowptr[d] + rank[e]] = src[e]; rank < deg so no sentinel collision.
// Blocks [FILL_BLOCKS, FILL_BLOCKS+MM_GRID): hw1' = fp16[(x @ W1) * dinv].
__global__ __launch_bounds__(256) void k_fillmm(
        const int* __restrict__ src, const int* __restrict__ dst,
        const int* __restrict__ rank, const int* __restrict__ rowptr,
        int* __restrict__ col,
        const float* __restrict__ h, const float* __restrict__ W,
        const float* __restrict__ dinv, __half* __restrict__ hw) {
    int bid = blockIdx.x;
    if (bid < FILL_BLOCKS) {
        int p = bid & 7;
        int lo = p * XCD_SLICE, hi = lo + XCD_SLICE;
        const int4* dst4 = (const int4*)dst;
        for (int i4 = (bid >> 3) * 256 + threadIdx.x; i4 < N_E4; i4 += SLICE_THREADS) {
            int4 d4 = dst4[i4];
            int e = i4 * 4;
            if (d4.x >= lo && d4.x < hi)
                col[rowptr[d4.x] + rank[e + 0]] = src[e + 0];
            if (d4.y >= lo && d4.y < hi)
                col[rowptr[d4.y] + rank[e + 1]] = src[e + 1];
            if (d4.z >= lo && d4.z < hi)
                col[rowptr[d4.z] + rank[e + 2]] = src[e + 2];
            if (d4.w >= lo && d4.w < hi)
                col[rowptr[d4.w] + rank[e + 3]] = src[e + 3];
        }
        return;
    }
    __shared__ float sW[64 * 64];
    __shared__ float sH[4 * 64];
    int t = threadIdx.x;
    const float4* W4 = (const float4*)W;
    float4* sW4 = (float4*)sW;
    for (int i = t; i < 1024; i += 256) sW4[i] = W4[i];
    int row0 = (bid - FILL_BLOCKS) * 4;
    int r = t >> 6, j = t & 63;
    sH[r * 64 + j] = h[(row0 + r) * 64 + j];
    __syncthreads();
    int i = row0 + r;
    float sum = 0.0f;
#pragma unroll
    for (int k = 0; k < 64; ++k) sum = fmaf(sH[r * 64 + k], sW[k * 64 + j], sum);
    hw[i * 64 + j] = __float2half_rn(sum * dinv[i]);
}

// ---------------- gather core: rows are multiples of 8 -> single full-ILP loop, no tail ----------------
__device__ __forceinline__ void gather2x4(
        const int* __restrict__ col, const uint4* __restrict__ hv,
        int rs, int re, int slot, int sub, float f[8]) {
    __half2 a0 = __float2half2_rn(0.f), a1 = a0, a2 = a0, a3 = a0;
    __half2 c0 = a0, c1 = a0, c2 = a0, c3 = a0;
    for (int e = rs; e < re; e += 8) {
        int s0 = __builtin_nontemporal_load(&col[e + slot]);
        int s1 = __builtin_nontemporal_load(&col[e + 2 + slot]);
        int s2 = __builtin_nontemporal_load(&col[e + 4 + slot]);
        int s3 = __builtin_nontemporal_load(&col[e + 6 + slot]);
        uint4 u0 = hv[(size_t)s0 * 8 + sub];
        uint4 u1 = hv[(size_t)s1 * 8 + sub];
        uint4 u2 = hv[(size_t)s2 * 8 + sub];
        uint4 u3 = hv[(size_t)s3 * 8 + sub];
        a0 = __hadd2(a0, *(__half2*)&u0.x); a1 = __hadd2(a1, *(__half2*)&u0.y);
        a2 = __hadd2(a2, *(__half2*)&u0.z); a3 = __hadd2(a3, *(__half2*)&u0.w);
        c0 = __hadd2(c0, *(__half2*)&u1.x); c1 = __hadd2(c1, *(__half2*)&u1.y);
        c2 = __hadd2(c2, *(__half2*)&u1.z); c3 = __hadd2(c3, *(__half2*)&u1.w);
        a0 = __hadd2(a0, *(__half2*)&u2.x); a1 = __hadd2(a1, *(__half2*)&u2.y);
        a2 = __hadd2(a2, *(__half2*)&u2.z); a3 = __hadd2(a3, *(__half2*)&u2.w);
        c0 = __hadd2(c0, *(__half2*)&u3.x); c1 = __hadd2(c1, *(__half2*)&u3.y);
        c2 = __hadd2(c2, *(__half2*)&u3.z); c3 = __hadd2(c3, *(__half2*)&u3.w);
    }
    a0 = __hadd2(a0, c0); a1 = __hadd2(a1, c1);
    a2 = __hadd2(a2, c2); a3 = __hadd2(a3, c3);
    a0 = __hadd2(a0, shx_h2(a0, 8));
    a1 = __hadd2(a1, shx_h2(a1, 8));
    a2 = __hadd2(a2, shx_h2(a2, 8));
    a3 = __hadd2(a3, shx_h2(a3, 8));
    float2 f0 = __half22float2(a0), f1 = __half22float2(a1);
    float2 f2 = __half22float2(a2), f3 = __half22float2(a3);
    f[0] = f0.x; f[1] = f0.y; f[2] = f1.x; f[3] = f1.y;
    f[4] = f2.x; f[5] = f2.y; f[6] = f3.x; f[7] = f3.y;
}

// ---------------- fused gather(4 nodes/wave) + relu + LDS matmul ----------------
__global__ __launch_bounds__(256) void k_gmm(
        const int* __restrict__ rowptr, const int* __restrict__ col,
        const float* __restrict__ dinv, const float* __restrict__ b,
        const __half* __restrict__ hw_in, const float* __restrict__ W,
        __half* __restrict__ hw_out) {
    __shared__ float sW[64 * 64];
    __shared__ float sA[16 * 64];
    int t = threadIdx.x;
    const float4* W4 = (const float4*)W;
    float4* sW4 = (float4*)sW;
    for (int i = t; i < 1024; i += 256) sW4[i] = W4[i];
    __syncthreads();

    int wave = t >> 6, lane = t & 63;
    int quarter = lane >> 4, slot = (lane >> 3) & 1, sub = lane & 7;
    int i0 = blockIdx.x * 16 + wave * 4;
    int i = i0 + quarter;
    float di = dinv[i];
    int rs = rowptr[i], re = rowptr[i + 1];
    const uint4* hv = (const uint4*)hw_in;

    float f[8];
    gather2x4(col, hv, rs, re, slot, sub, f);

    uint4 us = hv[(size_t)i * 8 + sub];
    float2 s0 = __half22float2(*(__half2*)&us.x);
    float2 s1 = __half22float2(*(__half2*)&us.y);
    float2 s2 = __half22float2(*(__half2*)&us.z);
    float2 s3 = __half22float2(*(__half2*)&us.w);
    float sf[8] = {s0.x, s0.y, s1.x, s1.y, s2.x, s2.y, s3.x, s3.y};
    float4 ba = ((const float4*)b)[sub * 2];
    float4 bb = ((const float4*)b)[sub * 2 + 1];
    float bf[8] = {ba.x, ba.y, ba.z, ba.w, bb.x, bb.y, bb.z, bb.w};
    if (slot == 0) {
        float r[8];
#pragma unroll
        for (int k = 0; k < 8; ++k) r[k] = fmaxf(fmaf(di, f[k] + sf[k], bf[k]), 0.f);
        *(float4*)&sA[(wave * 4 + quarter) * 64 + sub * 8]     = make_float4(r[0], r[1], r[2], r[3]);
        *(float4*)&sA[(wave * 4 + quarter) * 64 + sub * 8 + 4] = make_float4(r[4], r[5], r[6], r[7]);
    }

#pragma unroll
    for (int h = 0; h < 4; ++h) {
        const float4* sA4 = (const float4*)&sA[(wave * 4 + h) * 64];
        float sum = 0.f;
#pragma unroll
        for (int k4 = 0; k4 < 16; ++k4) {
            float4 a4 = sA4[k4];
            sum = fmaf(a4.x, sW[(k4 * 4 + 0) * 64 + lane], sum);
            sum = fmaf(a4.y, sW[(k4 * 4 + 1) * 64 + lane], sum);
            sum = fmaf(a4.z, sW[(k4 * 4 + 2) * 64 + lane], sum);
            sum = fmaf(a4.w, sW[(k4 * 4 + 3) * 64 + lane], sum);
        }
        hw_out[(size_t)(i0 + h) * 64 + lane] = __float2half_rn(sum * dinv[i0 + h]);
    }
}

// ---------------- layer-3 gather (4 nodes/wave; fp16 conv out) ----------------
__global__ __launch_bounds__(256) void k_gather3(
        const int* __restrict__ rowptr, const int* __restrict__ col,
        const float* __restrict__ dinv, const float* __restrict__ b,
        const __half* __restrict__ hw_in, __half* __restrict__ conv) {
    int t = threadIdx.x;
    int wave = t >> 6, lane = t & 63;
    int quarter = lane >> 4, slot = (lane >> 3) & 1, sub = lane & 7;
    int i = blockIdx.x * 16 + wave * 4 + quarter;
    float di = dinv[i];
    int rs = rowptr[i], re = rowptr[i + 1];
    const uint4* hv = (const uint4*)hw_in;

    float f[8];
    gather2x4(col, hv, rs, re, slot, sub, f);

    if (slot == 0) {
        uint4 us = hv[(size_t)i * 8 + sub];
        float2 s0 = __half22float2(*(__half2*)&us.x);
        float2 s1 = __half22float2(*(__half2*)&us.y);
        float2 s2 = __half22float2(*(__half2*)&us.z);
        float2 s3 = __half22float2(*(__half2*)&us.w);
        float sf[8] = {s0.x, s0.y, s1.x, s1.y, s2.x, s2.y, s3.x, s3.y};
        float4 ba = ((const float4*)b)[sub * 2];
        float4 bb = ((const float4*)b)[sub * 2 + 1];
        float bf[8] = {ba.x, ba.y, ba.z, ba.w, bb.x, bb.y, bb.z, bb.w};
        uint4 o;
        __half2* oh = (__half2*)&o;
#pragma unroll
        for (int c = 0; c < 4; ++c) {
            float r0 = fmaf(di, f[2 * c] + sf[2 * c], bf[2 * c]);
            float r1 = fmaf(di, f[2 * c + 1] + sf[2 * c + 1], bf[2 * c + 1]);
            oh[c] = __halves2half2(__float2half_rn(r0), __float2half_rn(r1));
        }
        ((uint4*)conv)[(size_t)i * 8 + sub] = o;
    }
}

// ---------------- fused mean-pool + dense + softmax + threshold: 8 graphs/block ----------------
__global__ __launch_bounds__(256) void k_dense(
        const __half* __restrict__ conv, const int* __restrict__ gstart,
        const float* __restrict__ Wd, const float* __restrict__ bd,
        float* __restrict__ out) {
    __shared__ float sp[8][64];
    __shared__ float red[8][4];
    int t = threadIdx.x;
    int wave = t >> 6, lane = t & 63;
    int g0 = blockIdx.x * 8;
#pragma unroll
    for (int gg = 0; gg < 2; ++gg) {
        int g = wave * 2 + gg;
        int n0 = gstart[g0 + g], n1 = gstart[g0 + g + 1];
        float acc = 0.f;
        int i = n0;
        for (; i + 1 < n1; i += 2) {
            float v0 = __half2float(conv[(size_t)i * 64 + lane]);
            float v1 = __half2float(conv[(size_t)(i + 1) * 64 + lane]);
            acc += v0 + v1;
        }
        if (i < n1) acc += __half2float(conv[(size_t)i * 64 + lane]);
        int n = n1 - n0;
        sp[g][lane] = (n > 0) ? acc / (float)n : 0.f;
    }
    __syncthreads();

    float acc[8][8];
#pragma unroll
    for (int r = 0; r < 8; ++r) {
        float bv = bd[r * 256 + t];
#pragma unroll
        for (int g = 0; g < 8; ++g) acc[g][r] = bv;
    }
    for (int k = 0; k < 64; ++k) {
        float w[8];
#pragma unroll
        for (int r = 0; r < 8; ++r) w[r] = Wd[k * BIOPRINT + r * 256 + t];
#pragma unroll
        for (int g = 0; g < 8; ++g) {
            float h = sp[g][k];
#pragma unroll
            for (int r = 0; r < 8; ++r) acc[g][r] = fmaf(h, w[r], acc[g][r]);
        }
    }
    float gm[8];
#pragma unroll
    for (int g = 0; g < 8; ++g) {
        float m = acc[g][0];
#pragma unroll
        for (int r = 1; r < 8; ++r) m = fmaxf(m, acc[g][r]);
#pragma unroll
        for (int off = 32; off > 0; off >>= 1) m = fmaxf(m, __shfl_xor(m, off));
        if (lane == 0) red[g][wave] = m;
    }
    __syncthreads();
#pragma unroll
    for (int g = 0; g < 8; ++g)
        gm[g] = fmaxf(fmaxf(red[g][0], red[g][1]), fmaxf(red[g][2], red[g][3]));
    __syncthreads();
    float gs[8];
#pragma unroll
    for (int g = 0; g < 8; ++g) {
        float s = 0.f;
#pragma unroll
        for (int r = 0; r < 8; ++r) { acc[g][r] = expf(acc[g][r] - gm[g]); s += acc[g][r]; }
#pragma unroll
        for (int off = 32; off > 0; off >>= 1) s += __shfl_xor(s, off);
        if (lane == 0) red[g][wave] = s;
    }
    __syncthreads();
#pragma unroll
    for (int g = 0; g < 8; ++g)
        gs[g] = red[g][0] + red[g][1] + red[g][2] + red[g][3];
#pragma unroll
    for (int g = 0; g < 8; ++g)
#pragma unroll
        for (int r = 0; r < 8; ++r) {
            float p = acc[g][r] / gs[g];
            out[(size_t)(g0 + g) * BIOPRINT + r * 256 + t] = (p >= 0.5f) ? 1.0f : 0.0f;
        }
}

// ---------------- launch ----------------

extern "C" void kernel_launch(void* const* d_in, const int* in_sizes, int n_in,
                              void* d_out, int out_size, void* d_ws, size_t ws_size,
                              hipStream_t stream) {
    const float* x     = (const float*)d_in[0];
    const int*   ei    = (const int*)d_in[1];
    const int*   batch = (const int*)d_in[2];
    const float* W1 = (const float*)d_in[3];
    const float* b1 = (const float*)d_in[4];
    const float* W2 = (const float*)d_in[5];
    const float* b2 = (const float*)d_in[6];
    const float* W3 = (const float*)d_in[7];
    const float* b3 = (const float*)d_in[8];
    const float* Wd = (const float*)d_in[9];
    const float* bd = (const float*)d_in[10];
    float* out = (float*)d_out;

    const int* src = ei;
    const int* dst = ei + N_EDGES;

    char* ws = (char*)d_ws;
    size_t off = 0;
    auto alloc = [&](size_t bytes) {
        void* p = ws + off;
        off += (bytes + 255) & ~(size_t)255;
        return p;
    };
    int*    deg    = (int*)alloc(N_NODES * sizeof(int));
    float*  dinv   = (float*)alloc(N_NODES * sizeof(float));
    int*    rowptr = (int*)alloc((N_NODES + 1) * sizeof(int));
    int*    bsum   = (int*)alloc(128 * sizeof(int));
    int*    rank   = (int*)alloc((size_t)N_EDGES * sizeof(int));
    int*    gstart = (int*)alloc((N_GRAPHS + 1) * sizeof(int));
    int*    col    = (int*)alloc((size_t)COL_CAP * sizeof(int));
    __half* bufA   = (__half*)alloc((size_t)(N_NODES + 1) * HIDDEN * sizeof(__half));
    __half* bufB   = (__half*)alloc((size_t)(N_NODES + 1) * HIDDEN * sizeof(__half));
    __half* conv   = (__half*)alloc((size_t)N_NODES * HIDDEN * sizeof(__half));

    hipMemsetAsync(deg, 0, N_NODES * sizeof(int), stream);
    // zero sentinel feature rows (read by padded gathers; never written by mm kernels)
    hipMemsetAsync(bufA + (size_t)N_NODES * HIDDEN, 0, HIDDEN * sizeof(__half), stream);
    hipMemsetAsync(bufB + (size_t)N_NODES * HIDDEN, 0, HIDDEN * sizeof(__half), stream);

    k_deg<<<DEG_BLOCKS, 256, 0, stream>>>(dst, deg, rank);
    k_scan1<<<N_SCAN_BLOCKS, SCAN_BLK, 0, stream>>>(deg, rowptr, bsum, dinv, N_NODES);
    k_scan3<<<N_SCAN_BLOCKS + 2, SCAN_BLK, 0, stream>>>(rowptr, deg, bsum, col,
                                                        batch, gstart, N_NODES);
    // atomic-free fill + layer-1 matmul fused (independent work, co-scheduled)
    k_fillmm<<<FILL_BLOCKS + MM_GRID, 256, 0, stream>>>(src, dst, rank, rowptr, col,
                                                        x, W1, dinv, bufA);

    const int g16_grid = N_NODES / 16;         // 6250 (16 nodes/block)
    k_gmm<<<g16_grid, 256, 0, stream>>>(rowptr, col, dinv, b1, bufA, W2, bufB);
    k_gmm<<<g16_grid, 256, 0, stream>>>(rowptr, col, dinv, b2, bufB, W3, bufA);
    k_gather3<<<g16_grid, 256, 0, stream>>>(rowptr, col, dinv, b3, bufA, conv);
    k_dense<<<N_GRAPHS / 8, 256, 0, stream>>>(conv, gstart, Wd, bd, out);
}

// Round 3
// 413.586 us; speedup vs baseline: 1.1937x; 1.0700x over previous
//
#include <hip/hip_runtime.h>
#include <hip/hip_fp16.h>
#include <math.h>

#define N_NODES   100000
#define N_EDGES   1600000
#define N_FEAT    64
#define HIDDEN    64
#define BIOPRINT  2048
#define N_GRAPHS  1024

#define SENTINEL  N_NODES                                      // zero feature row
#define COL_CAP   (N_EDGES + 8 * N_NODES)                      // padded col capacity

#define SCAN_BLK  1024
#define N_SCAN_BLOCKS ((N_NODES + SCAN_BLK - 1) / SCAN_BLK)   // 98
#define XCD_SLICE 12500                                        // nodes per XCD slice
#define FILL_BLOCKS 2000                                       // 250 blocks x 8 slices
#define SLICE_THREADS (250 * 256)                              // threads per slice
#define MM_GRID (N_NODES / 4)                                  // 25000
#define N_E4 (N_EDGES / 4)                                     // 400000
#define DEG_BLOCKS ((N_E4 + 255) / 256)                        // 1563

__device__ __forceinline__ __half2 shx_h2(__half2 v, int m) {
    int x = __shfl_xor(*(int*)&v, m);
    return *(__half2*)&x;
}

// ---------------- degree + edge rank: atomicAdd's return value IS the rank ----------------

__global__ __launch_bounds__(256) void k_deg(const int* __restrict__ dst,
                                             int* __restrict__ deg,
                                             int* __restrict__ rank) {
    int tid = blockIdx.x * blockDim.x + threadIdx.x;
    if (tid >= N_E4) return;
    int4 d4 = ((const int4*)dst)[tid];
    int4 r4;
    r4.x = atomicAdd(&deg[d4.x], 1);
    r4.y = atomicAdd(&deg[d4.y], 1);
    r4.z = atomicAdd(&deg[d4.z], 1);
    r4.w = atomicAdd(&deg[d4.w], 1);
    ((int4*)rank)[tid] = r4;   // coalesced full-line store
}

// ---------------- CSR build over PADDED degrees (rows padded to multiple of 8) ----------------

__global__ __launch_bounds__(SCAN_BLK) void k_scan1(
        const int* __restrict__ deg, int* __restrict__ incl,
        int* __restrict__ bsum, float* __restrict__ dinv, int n) {
    __shared__ int tmp[SCAN_BLK];
    int t = threadIdx.x;
    int i = blockIdx.x * SCAN_BLK + t;
    int v = (i < n) ? deg[i] : 0;
    if (i < n) dinv[i] = rsqrtf((float)v + 1.0f);
    int vp = (v + 7) & ~7;          // padded degree
    tmp[t] = vp;
    __syncthreads();
    for (int off = 1; off < SCAN_BLK; off <<= 1) {
        int u = (t >= off) ? tmp[t - off] : 0;
        __syncthreads();
        tmp[t] += u;
        __syncthreads();
    }
    if (i < n) incl[i] = tmp[t];
    if (t == SCAN_BLK - 1) bsum[blockIdx.x] = tmp[t];
}

__global__ __launch_bounds__(SCAN_BLK) void k_scan3(
        int* __restrict__ rowptr, const int* __restrict__ deg,
        const int* __restrict__ bsum, int* __restrict__ col,
        const int* __restrict__ batch, int* __restrict__ gstart, int n) {
    int t = threadIdx.x;
    int bid = blockIdx.x;
    if (bid >= N_SCAN_BLOCKS) {
        int g = (bid - N_SCAN_BLOCKS) * SCAN_BLK + t;
        if (g > N_GRAPHS) return;
        if (g == N_GRAPHS) { gstart[g] = N_NODES; return; }
        int lo = 0, hi = N_NODES;
        while (lo < hi) { int mid = (lo + hi) >> 1; if (batch[mid] < g) lo = mid + 1; else hi = mid; }
        gstart[g] = lo;
        return;
    }
    __shared__ int sb[128];
    if (t < 128) sb[t] = (t < N_SCAN_BLOCKS) ? bsum[t] : 0;
    __syncthreads();
    for (int off = 1; off < 128; off <<= 1) {
        int u = (t >= off && t < 128) ? sb[t - off] : 0;
        __syncthreads();
        if (t < 128) sb[t] += u;
        __syncthreads();
    }
    int base = (bid == 0) ? 0 : sb[bid - 1];
    int i = bid * SCAN_BLK + t;
    if (i < n) {
        int v = deg[i];
        int vp = (v + 7) & ~7;
        int ex = rowptr[i] - vp + base;   // exclusive padded start
        rowptr[i] = ex;
        // sentinel-fill the pad region [ex+v, ex+vp): nearly-sequential across threads
        for (int j = v; j < vp; ++j) col[ex + j] = SENTINEL;
    }
    if (bid == 0 && t == 0) rowptr[n] = sb[N_SCAN_BLOCKS - 1];  // padded total
}

// ---------------- fat kernel: XCD-sliced atomic-free fill + layer-1 matmul ----------------
__global__ __launch_bounds__(256) void k_fillmm(
        const int* __restrict__ src, const int* __restrict__ dst,
        const int* __restrict__ rank, const int* __restrict__ rowptr,
        int* __restrict__ col,
        const float* __restrict__ h, const float* __restrict__ W,
        const float* __restrict__ dinv, __half* __restrict__ hw) {
    int bid = blockIdx.x;
    if (bid < FILL_BLOCKS) {
        int p = bid & 7;
        int lo = p * XCD_SLICE, hi = lo + XCD_SLICE;
        const int4* dst4 = (const int4*)dst;
        for (int i4 = (bid >> 3) * 256 + threadIdx.x; i4 < N_E4; i4 += SLICE_THREADS) {
            int4 d4 = dst4[i4];
            int e = i4 * 4;
            if (d4.x >= lo && d4.x < hi)
                col[rowptr[d4.x] + rank[e + 0]] = src[e + 0];
            if (d4.y >= lo && d4.y < hi)
                col[rowptr[d4.y] + rank[e + 1]] = src[e + 1];
            if (d4.z >= lo && d4.z < hi)
                col[rowptr[d4.z] + rank[e + 2]] = src[e + 2];
            if (d4.w >= lo && d4.w < hi)
                col[rowptr[d4.w] + rank[e + 3]] = src[e + 3];
        }
        return;
    }
    __shared__ float sW[64 * 64];
    __shared__ float sH[4 * 64];
    int t = threadIdx.x;
    const float4* W4 = (const float4*)W;
    float4* sW4 = (float4*)sW;
    for (int i = t; i < 1024; i += 256) sW4[i] = W4[i];
    int row0 = (bid - FILL_BLOCKS) * 4;
    int r = t >> 6, j = t & 63;
    sH[r * 64 + j] = h[(row0 + r) * 64 + j];
    __syncthreads();
    int i = row0 + r;
    float sum = 0.0f;
#pragma unroll
    for (int k = 0; k < 64; ++k) sum = fmaf(sH[r * 64 + k], sW[k * 64 + j], sum);
    hw[i * 64 + j] = __float2half_rn(sum * dinv[i]);
}

// ---------------- gather core: rows are multiples of 8 -> single full-ILP loop, no tail ----------------
__device__ __forceinline__ void gather2x4(
        const int* __restrict__ col, const uint4* __restrict__ hv,
        int rs, int re, int slot, int sub, float f[8]) {
    __half2 a0 = __float2half2_rn(0.f), a1 = a0, a2 = a0, a3 = a0;
    __half2 c0 = a0, c1 = a0, c2 = a0, c3 = a0;
    for (int e = rs; e < re; e += 8) {
        int s0 = __builtin_nontemporal_load(&col[e + slot]);
        int s1 = __builtin_nontemporal_load(&col[e + 2 + slot]);
        int s2 = __builtin_nontemporal_load(&col[e + 4 + slot]);
        int s3 = __builtin_nontemporal_load(&col[e + 6 + slot]);
        uint4 u0 = hv[(size_t)s0 * 8 + sub];
        uint4 u1 = hv[(size_t)s1 * 8 + sub];
        uint4 u2 = hv[(size_t)s2 * 8 + sub];
        uint4 u3 = hv[(size_t)s3 * 8 + sub];
        a0 = __hadd2(a0, *(__half2*)&u0.x); a1 = __hadd2(a1, *(__half2*)&u0.y);
        a2 = __hadd2(a2, *(__half2*)&u0.z); a3 = __hadd2(a3, *(__half2*)&u0.w);
        c0 = __hadd2(c0, *(__half2*)&u1.x); c1 = __hadd2(c1, *(__half2*)&u1.y);
        c2 = __hadd2(c2, *(__half2*)&u1.z); c3 = __hadd2(c3, *(__half2*)&u1.w);
        a0 = __hadd2(a0, *(__half2*)&u2.x); a1 = __hadd2(a1, *(__half2*)&u2.y);
        a2 = __hadd2(a2, *(__half2*)&u2.z); a3 = __hadd2(a3, *(__half2*)&u2.w);
        c0 = __hadd2(c0, *(__half2*)&u3.x); c1 = __hadd2(c1, *(__half2*)&u3.y);
        c2 = __hadd2(c2, *(__half2*)&u3.z); c3 = __hadd2(c3, *(__half2*)&u3.w);
    }
    a0 = __hadd2(a0, c0); a1 = __hadd2(a1, c1);
    a2 = __hadd2(a2, c2); a3 = __hadd2(a3, c3);
    a0 = __hadd2(a0, shx_h2(a0, 8));
    a1 = __hadd2(a1, shx_h2(a1, 8));
    a2 = __hadd2(a2, shx_h2(a2, 8));
    a3 = __hadd2(a3, shx_h2(a3, 8));
    float2 f0 = __half22float2(a0), f1 = __half22float2(a1);
    float2 f2 = __half22float2(a2), f3 = __half22float2(a3);
    f[0] = f0.x; f[1] = f0.y; f[2] = f1.x; f[3] = f1.y;
    f[4] = f2.x; f[5] = f2.y; f[6] = f3.x; f[7] = f3.y;
}

// ---------------- fused gather(4 nodes/wave) + relu + LDS matmul ----------------
__global__ __launch_bounds__(256) void k_gmm(
        const int* __restrict__ rowptr, const int* __restrict__ col,
        const float* __restrict__ dinv, const float* __restrict__ b,
        const __half* __restrict__ hw_in, const float* __restrict__ W,
        __half* __restrict__ hw_out) {
    __shared__ float sW[64 * 64];
    __shared__ float sA[16 * 64];
    int t = threadIdx.x;
    const float4* W4 = (const float4*)W;
    float4* sW4 = (float4*)sW;
    for (int i = t; i < 1024; i += 256) sW4[i] = W4[i];
    __syncthreads();

    int wave = t >> 6, lane = t & 63;
    int quarter = lane >> 4, slot = (lane >> 3) & 1, sub = lane & 7;
    int i0 = blockIdx.x * 16 + wave * 4;
    int i = i0 + quarter;
    float di = dinv[i];
    int rs = rowptr[i], re = rowptr[i + 1];
    const uint4* hv = (const uint4*)hw_in;

    float f[8];
    gather2x4(col, hv, rs, re, slot, sub, f);

    uint4 us = hv[(size_t)i * 8 + sub];
    float2 s0 = __half22float2(*(__half2*)&us.x);
    float2 s1 = __half22float2(*(__half2*)&us.y);
    float2 s2 = __half22float2(*(__half2*)&us.z);
    float2 s3 = __half22float2(*(__half2*)&us.w);
    float sf[8] = {s0.x, s0.y, s1.x, s1.y, s2.x, s2.y, s3.x, s3.y};
    float4 ba = ((const float4*)b)[sub * 2];
    float4 bb = ((const float4*)b)[sub * 2 + 1];
    float bf[8] = {ba.x, ba.y, ba.z, ba.w, bb.x, bb.y, bb.z, bb.w};
    if (slot == 0) {
        float r[8];
#pragma unroll
        for (int k = 0; k < 8; ++k) r[k] = fmaxf(fmaf(di, f[k] + sf[k], bf[k]), 0.f);
        *(float4*)&sA[(wave * 4 + quarter) * 64 + sub * 8]     = make_float4(r[0], r[1], r[2], r[3]);
        *(float4*)&sA[(wave * 4 + quarter) * 64 + sub * 8 + 4] = make_float4(r[4], r[5], r[6], r[7]);
    }

#pragma unroll
    for (int h = 0; h < 4; ++h) {
        const float4* sA4 = (const float4*)&sA[(wave * 4 + h) * 64];
        float sum = 0.f;
#pragma unroll
        for (int k4 = 0; k4 < 16; ++k4) {
            float4 a4 = sA4[k4];
            sum = fmaf(a4.x, sW[(k4 * 4 + 0) * 64 + lane], sum);
            sum = fmaf(a4.y, sW[(k4 * 4 + 1) * 64 + lane], sum);
            sum = fmaf(a4.z, sW[(k4 * 4 + 2) * 64 + lane], sum);
            sum = fmaf(a4.w, sW[(k4 * 4 + 3) * 64 + lane], sum);
        }
        hw_out[(size_t)(i0 + h) * 64 + lane] = __float2half_rn(sum * dinv[i0 + h]);
    }
}

// ---------------- layer-3 gather (4 nodes/wave; fp16 conv out) ----------------
__global__ __launch_bounds__(256) void k_gather3(
        const int* __restrict__ rowptr, const int* __restrict__ col,
        const float* __restrict__ dinv, const float* __restrict__ b,
        const __half* __restrict__ hw_in, __half* __restrict__ conv) {
    int t = threadIdx.x;
    int wave = t >> 6, lane = t & 63;
    int quarter = lane >> 4, slot = (lane >> 3) & 1, sub = lane & 7;
    int i = blockIdx.x * 16 + wave * 4 + quarter;
    float di = dinv[i];
    int rs = rowptr[i], re = rowptr[i + 1];
    const uint4* hv = (const uint4*)hw_in;

    float f[8];
    gather2x4(col, hv, rs, re, slot, sub, f);

    if (slot == 0) {
        uint4 us = hv[(size_t)i * 8 + sub];
        float2 s0 = __half22float2(*(__half2*)&us.x);
        float2 s1 = __half22float2(*(__half2*)&us.y);
        float2 s2 = __half22float2(*(__half2*)&us.z);
        float2 s3 = __half22float2(*(__half2*)&us.w);
        float sf[8] = {s0.x, s0.y, s1.x, s1.y, s2.x, s2.y, s3.x, s3.y};
        float4 ba = ((const float4*)b)[sub * 2];
        float4 bb = ((const float4*)b)[sub * 2 + 1];
        float bf[8] = {ba.x, ba.y, ba.z, ba.w, bb.x, bb.y, bb.z, bb.w};
        uint4 o;
        __half2* oh = (__half2*)&o;
#pragma unroll
        for (int c = 0; c < 4; ++c) {
            float r0 = fmaf(di, f[2 * c] + sf[2 * c], bf[2 * c]);
            float r1 = fmaf(di, f[2 * c + 1] + sf[2 * c + 1], bf[2 * c + 1]);
            oh[c] = __halves2half2(__float2half_rn(r0), __float2half_rn(r1));
        }
        ((uint4*)conv)[(size_t)i * 8 + sub] = o;
    }
}

// ---------------- fused mean-pool + dense + softmax + threshold: 1 graph/block ----------------
// 1024 blocks (vs 128 before): 4 blocks/CU, 16 waves/CU — latency actually hidden.
// Pool: 4 waves x 2 nodes/iter, half2 loads (256B coalesced per wave over contiguous rows).
__global__ __launch_bounds__(256) void k_dense(
        const __half* __restrict__ conv, const int* __restrict__ gstart,
        const float* __restrict__ Wd, const float* __restrict__ bd,
        float* __restrict__ out) {
    __shared__ float sred[4][64];
    __shared__ float sp[64];
    __shared__ float rmax[4];
    __shared__ float rsum[4];
    int t = threadIdx.x;
    int wave = t >> 6, lane = t & 63;
    int g = blockIdx.x;
    int n0 = gstart[g], n1 = gstart[g + 1];

    // ---- mean pool over contiguous node range [n0, n1) ----
    int fp = lane & 31;            // feature pair index (2 feats per lane)
    int par = lane >> 5;           // which of the 2 nodes this half-wave reads
    const __half2* conv2 = (const __half2*)conv;
    float2 acc2 = make_float2(0.f, 0.f);
    for (int i = n0 + wave * 2 + par; i < n1; i += 8) {
        float2 f = __half22float2(conv2[(size_t)i * 32 + fp]);
        acc2.x += f.x; acc2.y += f.y;
    }
    acc2.x += __shfl_xor(acc2.x, 32);   // combine the two node-parities
    acc2.y += __shfl_xor(acc2.y, 32);
    if (lane < 32) { sred[wave][2 * fp] = acc2.x; sred[wave][2 * fp + 1] = acc2.y; }
    __syncthreads();
    if (t < 64) {
        int n = n1 - n0;
        float s = sred[0][t] + sred[1][t] + sred[2][t] + sred[3][t];
        sp[t] = (n > 0) ? s / (float)n : 0.f;
    }
    __syncthreads();

    // ---- dense: 2048 logits, 8 per thread ----
    float acc[8];
#pragma unroll
    for (int r = 0; r < 8; ++r) acc[r] = bd[r * 256 + t];
    for (int k = 0; k < 64; ++k) {
        float h = sp[k];
#pragma unroll
        for (int r = 0; r < 8; ++r)
            acc[r] = fmaf(h, Wd[k * BIOPRINT + r * 256 + t], acc[r]);
    }

    // ---- softmax over 2048 within the block ----
    float m = acc[0];
#pragma unroll
    for (int r = 1; r < 8; ++r) m = fmaxf(m, acc[r]);
#pragma unroll
    for (int off = 32; off > 0; off >>= 1) m = fmaxf(m, __shfl_xor(m, off));
    if (lane == 0) rmax[wave] = m;
    __syncthreads();
    m = fmaxf(fmaxf(rmax[0], rmax[1]), fmaxf(rmax[2], rmax[3]));

    float s = 0.f;
#pragma unroll
    for (int r = 0; r < 8; ++r) { acc[r] = expf(acc[r] - m); s += acc[r]; }
#pragma unroll
    for (int off = 32; off > 0; off >>= 1) s += __shfl_xor(s, off);
    if (lane == 0) rsum[wave] = s;
    __syncthreads();
    s = rsum[0] + rsum[1] + rsum[2] + rsum[3];

#pragma unroll
    for (int r = 0; r < 8; ++r) {
        float p = acc[r] / s;
        out[(size_t)g * BIOPRINT + r * 256 + t] = (p >= 0.5f) ? 1.0f : 0.0f;
    }
}

// ---------------- launch ----------------

extern "C" void kernel_launch(void* const* d_in, const int* in_sizes, int n_in,
                              void* d_out, int out_size, void* d_ws, size_t ws_size,
                              hipStream_t stream) {
    const float* x     = (const float*)d_in[0];
    const int*   ei    = (const int*)d_in[1];
    const int*   batch = (const int*)d_in[2];
    const float* W1 = (const float*)d_in[3];
    const float* b1 = (const float*)d_in[4];
    const float* W2 = (const float*)d_in[5];
    const float* b2 = (const float*)d_in[6];
    const float* W3 = (const float*)d_in[7];
    const float* b3 = (const float*)d_in[8];
    const float* Wd = (const float*)d_in[9];
    const float* bd = (const float*)d_in[10];
    float* out = (float*)d_out;

    const int* src = ei;
    const int* dst = ei + N_EDGES;

    char* ws = (char*)d_ws;
    size_t off = 0;
    auto alloc = [&](size_t bytes) {
        void* p = ws + off;
        off += (bytes + 255) & ~(size_t)255;
        return p;
    };
    int*    deg    = (int*)alloc(N_NODES * sizeof(int));
    float*  dinv   = (float*)alloc(N_NODES * sizeof(float));
    int*    rowptr = (int*)alloc((N_NODES + 1) * sizeof(int));
    int*    bsum   = (int*)alloc(128 * sizeof(int));
    int*    rank   = (int*)alloc((size_t)N_EDGES * sizeof(int));
    int*    gstart = (int*)alloc((N_GRAPHS + 1) * sizeof(int));
    int*    col    = (int*)alloc((size_t)COL_CAP * sizeof(int));
    __half* bufA   = (__half*)alloc((size_t)(N_NODES + 1) * HIDDEN * sizeof(__half));
    __half* bufB   = (__half*)alloc((size_t)(N_NODES + 1) * HIDDEN * sizeof(__half));
    __half* conv   = (__half*)alloc((size_t)N_NODES * HIDDEN * sizeof(__half));

    hipMemsetAsync(deg, 0, N_NODES * sizeof(int), stream);
    // zero sentinel feature rows (read by padded gathers; never written by mm kernels)
    hipMemsetAsync(bufA + (size_t)N_NODES * HIDDEN, 0, HIDDEN * sizeof(__half), stream);
    hipMemsetAsync(bufB + (size_t)N_NODES * HIDDEN, 0, HIDDEN * sizeof(__half), stream);

    k_deg<<<DEG_BLOCKS, 256, 0, stream>>>(dst, deg, rank);
    k_scan1<<<N_SCAN_BLOCKS, SCAN_BLK, 0, stream>>>(deg, rowptr, bsum, dinv, N_NODES);
    k_scan3<<<N_SCAN_BLOCKS + 2, SCAN_BLK, 0, stream>>>(rowptr, deg, bsum, col,
                                                        batch, gstart, N_NODES);
    // atomic-free fill + layer-1 matmul fused (independent work, co-scheduled)
    k_fillmm<<<FILL_BLOCKS + MM_GRID, 256, 0, stream>>>(src, dst, rank, rowptr, col,
                                                        x, W1, dinv, bufA);

    const int g16_grid = N_NODES / 16;         // 6250 (16 nodes/block)
    k_gmm<<<g16_grid, 256, 0, stream>>>(rowptr, col, dinv, b1, bufA, W2, bufB);
    k_gmm<<<g16_grid, 256, 0, stream>>>(rowptr, col, dinv, b2, bufB, W3, bufA);
    k_gather3<<<g16_grid, 256, 0, stream>>>(rowptr, col, dinv, b3, bufA, conv);
    k_dense<<<N_GRAPHS, 256, 0, stream>>>(conv, gstart, Wd, bd, out);
}

// Round 4
// 398.093 us; speedup vs baseline: 1.2401x; 1.0389x over previous
//
#include <hip/hip_runtime.h>
#include <hip/hip_fp16.h>
#include <math.h>

#define N_NODES   100000
#define N_EDGES   1600000
#define N_FEAT    64
#define HIDDEN    64
#define BIOPRINT  2048
#define N_GRAPHS  1024

#define SENTINEL  N_NODES                                      // zero feature row
#define COL_CAP   (N_EDGES + 8 * N_NODES)                      // padded col capacity

#define SCAN_BLK  1024
#define N_SCAN_BLOCKS ((N_NODES + SCAN_BLK - 1) / SCAN_BLK)   // 98
#define N_E4 (N_EDGES / 4)                                     // 400000
#define FILL_BLOCKS ((N_E4 + 255) / 256)                       // 1563: ONE int4 per thread
#define MM_GRID16 (N_NODES / 16)                               // 6250
#define DEG_BLOCKS ((N_E4 + 255) / 256)                        // 1563

__device__ __forceinline__ __half2 shx_h2(__half2 v, int m) {
    int x = __shfl_xor(*(int*)&v, m);
    return *(__half2*)&x;
}

// ---------------- degree + edge rank: atomicAdd's return value IS the rank ----------------

__global__ __launch_bounds__(256) void k_deg(const int* __restrict__ dst,
                                             int* __restrict__ deg,
                                             int* __restrict__ rank) {
    int tid = blockIdx.x * blockDim.x + threadIdx.x;
    if (tid >= N_E4) return;
    int4 d4 = ((const int4*)dst)[tid];
    int4 r4;
    r4.x = atomicAdd(&deg[d4.x], 1);
    r4.y = atomicAdd(&deg[d4.y], 1);
    r4.z = atomicAdd(&deg[d4.z], 1);
    r4.w = atomicAdd(&deg[d4.w], 1);
    ((int4*)rank)[tid] = r4;   // coalesced full-line store
}

// ---------------- CSR build over PADDED degrees (rows padded to multiple of 8) ----------------

__global__ __launch_bounds__(SCAN_BLK) void k_scan1(
        const int* __restrict__ deg, int* __restrict__ incl,
        int* __restrict__ bsum, float* __restrict__ dinv, int n) {
    __shared__ int tmp[SCAN_BLK];
    int t = threadIdx.x;
    int i = blockIdx.x * SCAN_BLK + t;
    int v = (i < n) ? deg[i] : 0;
    if (i < n) dinv[i] = rsqrtf((float)v + 1.0f);
    int vp = (v + 7) & ~7;          // padded degree
    tmp[t] = vp;
    __syncthreads();
    for (int off = 1; off < SCAN_BLK; off <<= 1) {
        int u = (t >= off) ? tmp[t - off] : 0;
        __syncthreads();
        tmp[t] += u;
        __syncthreads();
    }
    if (i < n) incl[i] = tmp[t];
    if (t == SCAN_BLK - 1) bsum[blockIdx.x] = tmp[t];
}

__global__ __launch_bounds__(SCAN_BLK) void k_scan3(
        int* __restrict__ rowptr, const int* __restrict__ deg,
        const int* __restrict__ bsum, int* __restrict__ col,
        const int* __restrict__ batch, int* __restrict__ gstart, int n) {
    int t = threadIdx.x;
    int bid = blockIdx.x;
    if (bid >= N_SCAN_BLOCKS) {
        int g = (bid - N_SCAN_BLOCKS) * SCAN_BLK + t;
        if (g > N_GRAPHS) return;
        if (g == N_GRAPHS) { gstart[g] = N_NODES; return; }
        int lo = 0, hi = N_NODES;
        while (lo < hi) { int mid = (lo + hi) >> 1; if (batch[mid] < g) lo = mid + 1; else hi = mid; }
        gstart[g] = lo;
        return;
    }
    __shared__ int sb[128];
    if (t < 128) sb[t] = (t < N_SCAN_BLOCKS) ? bsum[t] : 0;
    __syncthreads();
    for (int off = 1; off < 128; off <<= 1) {
        int u = (t >= off && t < 128) ? sb[t - off] : 0;
        __syncthreads();
        if (t < 128) sb[t] += u;
        __syncthreads();
    }
    int base = (bid == 0) ? 0 : sb[bid - 1];
    int i = bid * SCAN_BLK + t;
    if (i < n) {
        int v = deg[i];
        int vp = (v + 7) & ~7;
        int ex = rowptr[i] - vp + base;   // exclusive padded start
        rowptr[i] = ex;
        // sentinel-fill the pad region [ex+v, ex+vp): nearly-sequential across threads
        for (int j = v; j < vp; ++j) col[ex + j] = SENTINEL;
    }
    if (bid == 0 && t == 0) rowptr[n] = sb[N_SCAN_BLOCKS - 1];  // padded total
}

// ---------------- fat kernel: single-pass atomic-free fill + 16-row layer-1 matmul ----------------
// Blocks [0, FILL_BLOCKS): ONE int4 edge-group per thread. dst/rank/src all int4-coalesced;
//   col[rowptr[d] + rank[e]] = src[e] scattered store (no stall; ranks globally unique).
// Blocks [FILL_BLOCKS, FILL_BLOCKS+MM_GRID16): hw1' = fp16[(x @ W1) * dinv], 16 rows/block
//   (4x less W1 LDS staging than 4-row blocks; broadcast b128 row reads).
__global__ __launch_bounds__(256) void k_fillmm(
        const int* __restrict__ src, const int* __restrict__ dst,
        const int* __restrict__ rank, const int* __restrict__ rowptr,
        int* __restrict__ col,
        const float* __restrict__ h, const float* __restrict__ W,
        const float* __restrict__ dinv, __half* __restrict__ hw) {
    int bid = blockIdx.x;
    if (bid < FILL_BLOCKS) {
        int tid = bid * 256 + threadIdx.x;
        if (tid < N_E4) {
            int4 d4 = ((const int4*)dst)[tid];
            int4 r4 = ((const int4*)rank)[tid];
            int4 s4 = ((const int4*)src)[tid];
            col[rowptr[d4.x] + r4.x] = s4.x;
            col[rowptr[d4.y] + r4.y] = s4.y;
            col[rowptr[d4.z] + r4.z] = s4.z;
            col[rowptr[d4.w] + r4.w] = s4.w;
        }
        return;
    }
    __shared__ float sW[64 * 64];
    __shared__ float sA[16 * 64];
    int t = threadIdx.x;
    const float4* W4 = (const float4*)W;
    float4* sW4 = (float4*)sW;
    for (int i = t; i < 1024; i += 256) sW4[i] = W4[i];
    int row0 = (bid - FILL_BLOCKS) * 16;
    ((float4*)sA)[t] = ((const float4*)h)[row0 * 16 + t];   // 16 rows x 64 f32 = 256 float4
    __syncthreads();
    int wave = t >> 6, lane = t & 63;
#pragma unroll
    for (int hh = 0; hh < 4; ++hh) {
        int row = row0 + wave * 4 + hh;
        const float4* sA4 = (const float4*)&sA[(wave * 4 + hh) * 64];
        float sum = 0.f;
#pragma unroll
        for (int k4 = 0; k4 < 16; ++k4) {
            float4 a4 = sA4[k4];                              // broadcast b128
            sum = fmaf(a4.x, sW[(k4 * 4 + 0) * 64 + lane], sum);
            sum = fmaf(a4.y, sW[(k4 * 4 + 1) * 64 + lane], sum);
            sum = fmaf(a4.z, sW[(k4 * 4 + 2) * 64 + lane], sum);
            sum = fmaf(a4.w, sW[(k4 * 4 + 3) * 64 + lane], sum);
        }
        hw[(size_t)row * 64 + lane] = __float2half_rn(sum * dinv[row]);
    }
}

// ---------------- gather core: rows are multiples of 8 -> single full-ILP loop, no tail ----------------
__device__ __forceinline__ void gather2x4(
        const int* __restrict__ col, const uint4* __restrict__ hv,
        int rs, int re, int slot, int sub, float f[8]) {
    __half2 a0 = __float2half2_rn(0.f), a1 = a0, a2 = a0, a3 = a0;
    __half2 c0 = a0, c1 = a0, c2 = a0, c3 = a0;
    for (int e = rs; e < re; e += 8) {
        int s0 = __builtin_nontemporal_load(&col[e + slot]);
        int s1 = __builtin_nontemporal_load(&col[e + 2 + slot]);
        int s2 = __builtin_nontemporal_load(&col[e + 4 + slot]);
        int s3 = __builtin_nontemporal_load(&col[e + 6 + slot]);
        uint4 u0 = hv[(size_t)s0 * 8 + sub];
        uint4 u1 = hv[(size_t)s1 * 8 + sub];
        uint4 u2 = hv[(size_t)s2 * 8 + sub];
        uint4 u3 = hv[(size_t)s3 * 8 + sub];
        a0 = __hadd2(a0, *(__half2*)&u0.x); a1 = __hadd2(a1, *(__half2*)&u0.y);
        a2 = __hadd2(a2, *(__half2*)&u0.z); a3 = __hadd2(a3, *(__half2*)&u0.w);
        c0 = __hadd2(c0, *(__half2*)&u1.x); c1 = __hadd2(c1, *(__half2*)&u1.y);
        c2 = __hadd2(c2, *(__half2*)&u1.z); c3 = __hadd2(c3, *(__half2*)&u1.w);
        a0 = __hadd2(a0, *(__half2*)&u2.x); a1 = __hadd2(a1, *(__half2*)&u2.y);
        a2 = __hadd2(a2, *(__half2*)&u2.z); a3 = __hadd2(a3, *(__half2*)&u2.w);
        c0 = __hadd2(c0, *(__half2*)&u3.x); c1 = __hadd2(c1, *(__half2*)&u3.y);
        c2 = __hadd2(c2, *(__half2*)&u3.z); c3 = __hadd2(c3, *(__half2*)&u3.w);
    }
    a0 = __hadd2(a0, c0); a1 = __hadd2(a1, c1);
    a2 = __hadd2(a2, c2); a3 = __hadd2(a3, c3);
    a0 = __hadd2(a0, shx_h2(a0, 8));
    a1 = __hadd2(a1, shx_h2(a1, 8));
    a2 = __hadd2(a2, shx_h2(a2, 8));
    a3 = __hadd2(a3, shx_h2(a3, 8));
    float2 f0 = __half22float2(a0), f1 = __half22float2(a1);
    float2 f2 = __half22float2(a2), f3 = __half22float2(a3);
    f[0] = f0.x; f[1] = f0.y; f[2] = f1.x; f[3] = f1.y;
    f[4] = f2.x; f[5] = f2.y; f[6] = f3.x; f[7] = f3.y;
}

// ---------------- fused gather(4 nodes/wave) + relu + LDS matmul ----------------
__global__ __launch_bounds__(256) void k_gmm(
        const int* __restrict__ rowptr, const int* __restrict__ col,
        const float* __restrict__ dinv, const float* __restrict__ b,
        const __half* __restrict__ hw_in, const float* __restrict__ W,
        __half* __restrict__ hw_out) {
    __shared__ float sW[64 * 64];
    __shared__ float sA[16 * 64];
    int t = threadIdx.x;
    const float4* W4 = (const float4*)W;
    float4* sW4 = (float4*)sW;
    for (int i = t; i < 1024; i += 256) sW4[i] = W4[i];
    __syncthreads();

    int wave = t >> 6, lane = t & 63;
    int quarter = lane >> 4, slot = (lane >> 3) & 1, sub = lane & 7;
    int i0 = blockIdx.x * 16 + wave * 4;
    int i = i0 + quarter;
    float di = dinv[i];
    int rs = rowptr[i], re = rowptr[i + 1];
    const uint4* hv = (const uint4*)hw_in;

    float f[8];
    gather2x4(col, hv, rs, re, slot, sub, f);

    uint4 us = hv[(size_t)i * 8 + sub];
    float2 s0 = __half22float2(*(__half2*)&us.x);
    float2 s1 = __half22float2(*(__half2*)&us.y);
    float2 s2 = __half22float2(*(__half2*)&us.z);
    float2 s3 = __half22float2(*(__half2*)&us.w);
    float sf[8] = {s0.x, s0.y, s1.x, s1.y, s2.x, s2.y, s3.x, s3.y};
    float4 ba = ((const float4*)b)[sub * 2];
    float4 bb = ((const float4*)b)[sub * 2 + 1];
    float bf[8] = {ba.x, ba.y, ba.z, ba.w, bb.x, bb.y, bb.z, bb.w};
    if (slot == 0) {
        float r[8];
#pragma unroll
        for (int k = 0; k < 8; ++k) r[k] = fmaxf(fmaf(di, f[k] + sf[k], bf[k]), 0.f);
        *(float4*)&sA[(wave * 4 + quarter) * 64 + sub * 8]     = make_float4(r[0], r[1], r[2], r[3]);
        *(float4*)&sA[(wave * 4 + quarter) * 64 + sub * 8 + 4] = make_float4(r[4], r[5], r[6], r[7]);
    }

#pragma unroll
    for (int h = 0; h < 4; ++h) {
        const float4* sA4 = (const float4*)&sA[(wave * 4 + h) * 64];
        float sum = 0.f;
#pragma unroll
        for (int k4 = 0; k4 < 16; ++k4) {
            float4 a4 = sA4[k4];
            sum = fmaf(a4.x, sW[(k4 * 4 + 0) * 64 + lane], sum);
            sum = fmaf(a4.y, sW[(k4 * 4 + 1) * 64 + lane], sum);
            sum = fmaf(a4.z, sW[(k4 * 4 + 2) * 64 + lane], sum);
            sum = fmaf(a4.w, sW[(k4 * 4 + 3) * 64 + lane], sum);
        }
        hw_out[(size_t)(i0 + h) * 64 + lane] = __float2half_rn(sum * dinv[i0 + h]);
    }
}

// ---------------- layer-3 gather (4 nodes/wave; fp16 conv out) ----------------
__global__ __launch_bounds__(256) void k_gather3(
        const int* __restrict__ rowptr, const int* __restrict__ col,
        const float* __restrict__ dinv, const float* __restrict__ b,
        const __half* __restrict__ hw_in, __half* __restrict__ conv) {
    int t = threadIdx.x;
    int wave = t >> 6, lane = t & 63;
    int quarter = lane >> 4, slot = (lane >> 3) & 1, sub = lane & 7;
    int i = blockIdx.x * 16 + wave * 4 + quarter;
    float di = dinv[i];
    int rs = rowptr[i], re = rowptr[i + 1];
    const uint4* hv = (const uint4*)hw_in;

    float f[8];
    gather2x4(col, hv, rs, re, slot, sub, f);

    if (slot == 0) {
        uint4 us = hv[(size_t)i * 8 + sub];
        float2 s0 = __half22float2(*(__half2*)&us.x);
        float2 s1 = __half22float2(*(__half2*)&us.y);
        float2 s2 = __half22float2(*(__half2*)&us.z);
        float2 s3 = __half22float2(*(__half2*)&us.w);
        float sf[8] = {s0.x, s0.y, s1.x, s1.y, s2.x, s2.y, s3.x, s3.y};
        float4 ba = ((const float4*)b)[sub * 2];
        float4 bb = ((const float4*)b)[sub * 2 + 1];
        float bf[8] = {ba.x, ba.y, ba.z, ba.w, bb.x, bb.y, bb.z, bb.w};
        uint4 o;
        __half2* oh = (__half2*)&o;
#pragma unroll
        for (int c = 0; c < 4; ++c) {
            float r0 = fmaf(di, f[2 * c] + sf[2 * c], bf[2 * c]);
            float r1 = fmaf(di, f[2 * c + 1] + sf[2 * c + 1], bf[2 * c + 1]);
            oh[c] = __halves2half2(__float2half_rn(r0), __float2half_rn(r1));
        }
        ((uint4*)conv)[(size_t)i * 8 + sub] = o;
    }
}

// ---------------- fused mean-pool + dense + softmax + threshold: 1 graph/block ----------------
__global__ __launch_bounds__(256) void k_dense(
        const __half* __restrict__ conv, const int* __restrict__ gstart,
        const float* __restrict__ Wd, const float* __restrict__ bd,
        float* __restrict__ out) {
    __shared__ float sred[4][64];
    __shared__ float sp[64];
    __shared__ float rmax[4];
    __shared__ float rsum[4];
    int t = threadIdx.x;
    int wave = t >> 6, lane = t & 63;
    int g = blockIdx.x;
    int n0 = gstart[g], n1 = gstart[g + 1];

    // ---- mean pool over contiguous node range [n0, n1) ----
    int fp = lane & 31;            // feature pair index (2 feats per lane)
    int par = lane >> 5;           // which of the 2 nodes this half-wave reads
    const __half2* conv2 = (const __half2*)conv;
    float2 acc2 = make_float2(0.f, 0.f);
    for (int i = n0 + wave * 2 + par; i < n1; i += 8) {
        float2 f = __half22float2(conv2[(size_t)i * 32 + fp]);
        acc2.x += f.x; acc2.y += f.y;
    }
    acc2.x += __shfl_xor(acc2.x, 32);   // combine the two node-parities
    acc2.y += __shfl_xor(acc2.y, 32);
    if (lane < 32) { sred[wave][2 * fp] = acc2.x; sred[wave][2 * fp + 1] = acc2.y; }
    __syncthreads();
    if (t < 64) {
        int n = n1 - n0;
        float s = sred[0][t] + sred[1][t] + sred[2][t] + sred[3][t];
        sp[t] = (n > 0) ? s / (float)n : 0.f;
    }
    __syncthreads();

    // ---- dense: 2048 logits, 8 per thread ----
    float acc[8];
#pragma unroll
    for (int r = 0; r < 8; ++r) acc[r] = bd[r * 256 + t];
    for (int k = 0; k < 64; ++k) {
        float h = sp[k];
#pragma unroll
        for (int r = 0; r < 8; ++r)
            acc[r] = fmaf(h, Wd[k * BIOPRINT + r * 256 + t], acc[r]);
    }

    // ---- softmax over 2048 within the block ----
    float m = acc[0];
#pragma unroll
    for (int r = 1; r < 8; ++r) m = fmaxf(m, acc[r]);
#pragma unroll
    for (int off = 32; off > 0; off >>= 1) m = fmaxf(m, __shfl_xor(m, off));
    if (lane == 0) rmax[wave] = m;
    __syncthreads();
    m = fmaxf(fmaxf(rmax[0], rmax[1]), fmaxf(rmax[2], rmax[3]));

    float s = 0.f;
#pragma unroll
    for (int r = 0; r < 8; ++r) { acc[r] = expf(acc[r] - m); s += acc[r]; }
#pragma unroll
    for (int off = 32; off > 0; off >>= 1) s += __shfl_xor(s, off);
    if (lane == 0) rsum[wave] = s;
    __syncthreads();
    s = rsum[0] + rsum[1] + rsum[2] + rsum[3];

#pragma unroll
    for (int r = 0; r < 8; ++r) {
        float p = acc[r] / s;
        out[(size_t)g * BIOPRINT + r * 256 + t] = (p >= 0.5f) ? 1.0f : 0.0f;
    }
}

// ---------------- launch ----------------

extern "C" void kernel_launch(void* const* d_in, const int* in_sizes, int n_in,
                              void* d_out, int out_size, void* d_ws, size_t ws_size,
                              hipStream_t stream) {
    const float* x     = (const float*)d_in[0];
    const int*   ei    = (const int*)d_in[1];
    const int*   batch = (const int*)d_in[2];
    const float* W1 = (const float*)d_in[3];
    const float* b1 = (const float*)d_in[4];
    const float* W2 = (const float*)d_in[5];
    const float* b2 = (const float*)d_in[6];
    const float* W3 = (const float*)d_in[7];
    const float* b3 = (const float*)d_in[8];
    const float* Wd = (const float*)d_in[9];
    const float* bd = (const float*)d_in[10];
    float* out = (float*)d_out;

    const int* src = ei;
    const int* dst = ei + N_EDGES;

    char* ws = (char*)d_ws;
    size_t off = 0;
    auto alloc = [&](size_t bytes) {
        void* p = ws + off;
        off += (bytes + 255) & ~(size_t)255;
        return p;
    };
    int*    deg    = (int*)alloc(N_NODES * sizeof(int));
    float*  dinv   = (float*)alloc(N_NODES * sizeof(float));
    int*    rowptr = (int*)alloc((N_NODES + 1) * sizeof(int));
    int*    bsum   = (int*)alloc(128 * sizeof(int));
    int*    rank   = (int*)alloc((size_t)N_EDGES * sizeof(int));
    int*    gstart = (int*)alloc((N_GRAPHS + 1) * sizeof(int));
    int*    col    = (int*)alloc((size_t)COL_CAP * sizeof(int));
    __half* bufA   = (__half*)alloc((size_t)(N_NODES + 1) * HIDDEN * sizeof(__half));
    __half* bufB   = (__half*)alloc((size_t)(N_NODES + 1) * HIDDEN * sizeof(__half));
    __half* conv   = (__half*)alloc((size_t)N_NODES * HIDDEN * sizeof(__half));

    hipMemsetAsync(deg, 0, N_NODES * sizeof(int), stream);
    // zero sentinel feature rows (read by padded gathers; never written by mm kernels)
    hipMemsetAsync(bufA + (size_t)N_NODES * HIDDEN, 0, HIDDEN * sizeof(__half), stream);
    hipMemsetAsync(bufB + (size_t)N_NODES * HIDDEN, 0, HIDDEN * sizeof(__half), stream);

    k_deg<<<DEG_BLOCKS, 256, 0, stream>>>(dst, deg, rank);
    k_scan1<<<N_SCAN_BLOCKS, SCAN_BLK, 0, stream>>>(deg, rowptr, bsum, dinv, N_NODES);
    k_scan3<<<N_SCAN_BLOCKS + 2, SCAN_BLK, 0, stream>>>(rowptr, deg, bsum, col,
                                                        batch, gstart, N_NODES);
    // single-pass atomic-free fill + 16-row layer-1 matmul fused
    k_fillmm<<<FILL_BLOCKS + MM_GRID16, 256, 0, stream>>>(src, dst, rank, rowptr, col,
                                                          x, W1, dinv, bufA);

    const int g16_grid = N_NODES / 16;         // 6250 (16 nodes/block)
    k_gmm<<<g16_grid, 256, 0, stream>>>(rowptr, col, dinv, b1, bufA, W2, bufB);
    k_gmm<<<g16_grid, 256, 0, stream>>>(rowptr, col, dinv, b2, bufB, W3, bufA);
    k_gather3<<<g16_grid, 256, 0, stream>>>(rowptr, col, dinv, b3, bufA, conv);
    k_dense<<<N_GRAPHS, 256, 0, stream>>>(conv, gstart, Wd, bd, out);
}

// Round 5
// 353.949 us; speedup vs baseline: 1.3948x; 1.1247x over previous
//
#include <hip/hip_runtime.h>
#include <hip/hip_fp16.h>
#include <math.h>

#define N_NODES   100000
#define N_EDGES   1600000
#define N_FEAT    64
#define HIDDEN    64
#define BIOPRINT  2048
#define N_GRAPHS  1024

#define SENTINEL  N_NODES                                      // zero feature row
#define COL_CAP   (N_EDGES + 8 * N_NODES)                      // padded col capacity

#define SCAN_BLK  1024
#define N_SCAN_BLOCKS ((N_NODES + SCAN_BLK - 1) / SCAN_BLK)   // 98
#define N_E4 (N_EDGES / 4)                                     // 400000
#define FILL_BLOCKS ((N_E4 + 255) / 256)                       // 1563: ONE int4 per thread
#define MM_ROWS   32                                           // rows per mm block in k_fillmm
#define MM_GRID32 (N_NODES / MM_ROWS)                          // 3125
#define DEG_BLOCKS ((N_E4 + 255) / 256)                        // 1563

__device__ __forceinline__ __half2 shx_h2(__half2 v, int m) {
    int x = __shfl_xor(*(int*)&v, m);
    return *(__half2*)&x;
}

// Stage W (64x64 f32, row-major) into LDS permuted as sW[k4][col][k&3]:
// one thread's 4 per-k4 weights for its column become one contiguous float4.
__device__ __forceinline__ void stage_w_perm(const float* __restrict__ W, float* sW, int t) {
    const float4* W4 = (const float4*)W;
    for (int i = t; i < 1024; i += 256) {
        float4 w = W4[i];                  // W[k][4c..4c+3], k=i>>4, c=i&15
        int k = i >> 4;
        int c4 = (i & 15) * 4;
        int base = (k >> 2) * 256 + (k & 3);
        sW[base + (c4 + 0) * 4] = w.x;
        sW[base + (c4 + 1) * 4] = w.y;
        sW[base + (c4 + 2) * 4] = w.z;
        sW[base + (c4 + 3) * 4] = w.w;
    }
}

// ---------------- degree + edge rank: atomicAdd's return value IS the rank ----------------

__global__ __launch_bounds__(256) void k_deg(const int* __restrict__ dst,
                                             int* __restrict__ deg,
                                             int* __restrict__ rank) {
    int tid = blockIdx.x * blockDim.x + threadIdx.x;
    if (tid >= N_E4) return;
    int4 d4 = ((const int4*)dst)[tid];
    int4 r4;
    r4.x = atomicAdd(&deg[d4.x], 1);
    r4.y = atomicAdd(&deg[d4.y], 1);
    r4.z = atomicAdd(&deg[d4.z], 1);
    r4.w = atomicAdd(&deg[d4.w], 1);
    ((int4*)rank)[tid] = r4;   // coalesced full-line store
}

// ---------------- CSR build over PADDED degrees (rows padded to multiple of 8) ----------------

__global__ __launch_bounds__(SCAN_BLK) void k_scan1(
        const int* __restrict__ deg, int* __restrict__ incl,
        int* __restrict__ bsum, float* __restrict__ dinv, int n) {
    __shared__ int tmp[SCAN_BLK];
    int t = threadIdx.x;
    int i = blockIdx.x * SCAN_BLK + t;
    int v = (i < n) ? deg[i] : 0;
    if (i < n) dinv[i] = rsqrtf((float)v + 1.0f);
    int vp = (v + 7) & ~7;          // padded degree
    tmp[t] = vp;
    __syncthreads();
    for (int off = 1; off < SCAN_BLK; off <<= 1) {
        int u = (t >= off) ? tmp[t - off] : 0;
        __syncthreads();
        tmp[t] += u;
        __syncthreads();
    }
    if (i < n) incl[i] = tmp[t];
    if (t == SCAN_BLK - 1) bsum[blockIdx.x] = tmp[t];
}

__global__ __launch_bounds__(SCAN_BLK) void k_scan3(
        int* __restrict__ rowptr, const int* __restrict__ deg,
        const int* __restrict__ bsum, int* __restrict__ col,
        const int* __restrict__ batch, int* __restrict__ gstart, int n) {
    int t = threadIdx.x;
    int bid = blockIdx.x;
    if (bid >= N_SCAN_BLOCKS) {
        int g = (bid - N_SCAN_BLOCKS) * SCAN_BLK + t;
        if (g > N_GRAPHS) return;
        if (g == N_GRAPHS) { gstart[g] = N_NODES; return; }
        int lo = 0, hi = N_NODES;
        while (lo < hi) { int mid = (lo + hi) >> 1; if (batch[mid] < g) lo = mid + 1; else hi = mid; }
        gstart[g] = lo;
        return;
    }
    __shared__ int sb[128];
    if (t < 128) sb[t] = (t < N_SCAN_BLOCKS) ? bsum[t] : 0;
    __syncthreads();
    for (int off = 1; off < 128; off <<= 1) {
        int u = (t >= off && t < 128) ? sb[t - off] : 0;
        __syncthreads();
        if (t < 128) sb[t] += u;
        __syncthreads();
    }
    int base = (bid == 0) ? 0 : sb[bid - 1];
    int i = bid * SCAN_BLK + t;
    if (i < n) {
        int v = deg[i];
        int vp = (v + 7) & ~7;
        int ex = rowptr[i] - vp + base;   // exclusive padded start
        rowptr[i] = ex;
        // sentinel-fill the pad region [ex+v, ex+vp): nearly-sequential across threads
        for (int j = v; j < vp; ++j) col[ex + j] = SENTINEL;
    }
    if (bid == 0 && t == 0) rowptr[n] = sb[N_SCAN_BLOCKS - 1];  // padded total
}

// ---------------- fat kernel: single-pass atomic-free fill + 32-row layer-1 matmul ----------------
// Blocks [0, FILL_BLOCKS): ONE int4 edge-group per thread, atomic-free scatter.
// Blocks [FILL_BLOCKS, FILL_BLOCKS+MM_GRID32): hw1' = fp16[(x @ W1) * dinv], 32 rows/block.
//   Permuted sW + k4-outer loop: W read ONCE per thread as b128; sA via broadcast b128.
__global__ __launch_bounds__(256) void k_fillmm(
        const int* __restrict__ src, const int* __restrict__ dst,
        const int* __restrict__ rank, const int* __restrict__ rowptr,
        int* __restrict__ col,
        const float* __restrict__ h, const float* __restrict__ W,
        const float* __restrict__ dinv, __half* __restrict__ hw) {
    int bid = blockIdx.x;
    if (bid < FILL_BLOCKS) {
        int tid = bid * 256 + threadIdx.x;
        if (tid < N_E4) {
            int4 d4 = ((const int4*)dst)[tid];
            int4 r4 = ((const int4*)rank)[tid];
            int4 s4 = ((const int4*)src)[tid];
            col[rowptr[d4.x] + r4.x] = s4.x;
            col[rowptr[d4.y] + r4.y] = s4.y;
            col[rowptr[d4.z] + r4.z] = s4.z;
            col[rowptr[d4.w] + r4.w] = s4.w;
        }
        return;
    }
    __shared__ float sW[64 * 64];
    __shared__ float sA[MM_ROWS * 64];
    int t = threadIdx.x;
    stage_w_perm(W, sW, t);
    int row0 = (bid - FILL_BLOCKS) * MM_ROWS;
    ((float4*)sA)[t]       = ((const float4*)h)[row0 * 16 + t];
    ((float4*)sA)[t + 256] = ((const float4*)h)[row0 * 16 + t + 256];
    __syncthreads();
    int wave = t >> 6, lane = t & 63;
    const float4* sWp = (const float4*)sW;     // [k4*64 + lane]
    float sum[8] = {0.f, 0.f, 0.f, 0.f, 0.f, 0.f, 0.f, 0.f};
#pragma unroll
    for (int k4 = 0; k4 < 16; ++k4) {
        float4 w4 = sWp[k4 * 64 + lane];       // W[k4*4..+3][lane], read once
#pragma unroll
        for (int hh = 0; hh < 8; ++hh) {
            float4 a4 = ((const float4*)&sA[(wave * 8 + hh) * 64])[k4];   // broadcast
            sum[hh] = fmaf(a4.x, w4.x, sum[hh]);
            sum[hh] = fmaf(a4.y, w4.y, sum[hh]);
            sum[hh] = fmaf(a4.z, w4.z, sum[hh]);
            sum[hh] = fmaf(a4.w, w4.w, sum[hh]);
        }
    }
#pragma unroll
    for (int hh = 0; hh < 8; ++hh) {
        int row = row0 + wave * 8 + hh;
        hw[(size_t)row * 64 + lane] = __float2half_rn(sum[hh] * dinv[row]);
    }
}

// ---------------- gather core: rows are multiples of 8 -> single full-ILP loop, no tail ----------------
__device__ __forceinline__ void gather2x4(
        const int* __restrict__ col, const uint4* __restrict__ hv,
        int rs, int re, int slot, int sub, float f[8]) {
    __half2 a0 = __float2half2_rn(0.f), a1 = a0, a2 = a0, a3 = a0;
    __half2 c0 = a0, c1 = a0, c2 = a0, c3 = a0;
    for (int e = rs; e < re; e += 8) {
        int s0 = __builtin_nontemporal_load(&col[e + slot]);
        int s1 = __builtin_nontemporal_load(&col[e + 2 + slot]);
        int s2 = __builtin_nontemporal_load(&col[e + 4 + slot]);
        int s3 = __builtin_nontemporal_load(&col[e + 6 + slot]);
        uint4 u0 = hv[(size_t)s0 * 8 + sub];
        uint4 u1 = hv[(size_t)s1 * 8 + sub];
        uint4 u2 = hv[(size_t)s2 * 8 + sub];
        uint4 u3 = hv[(size_t)s3 * 8 + sub];
        a0 = __hadd2(a0, *(__half2*)&u0.x); a1 = __hadd2(a1, *(__half2*)&u0.y);
        a2 = __hadd2(a2, *(__half2*)&u0.z); a3 = __hadd2(a3, *(__half2*)&u0.w);
        c0 = __hadd2(c0, *(__half2*)&u1.x); c1 = __hadd2(c1, *(__half2*)&u1.y);
        c2 = __hadd2(c2, *(__half2*)&u1.z); c3 = __hadd2(c3, *(__half2*)&u1.w);
        a0 = __hadd2(a0, *(__half2*)&u2.x); a1 = __hadd2(a1, *(__half2*)&u2.y);
        a2 = __hadd2(a2, *(__half2*)&u2.z); a3 = __hadd2(a3, *(__half2*)&u2.w);
        c0 = __hadd2(c0, *(__half2*)&u3.x); c1 = __hadd2(c1, *(__half2*)&u3.y);
        c2 = __hadd2(c2, *(__half2*)&u3.z); c3 = __hadd2(c3, *(__half2*)&u3.w);
    }
    a0 = __hadd2(a0, c0); a1 = __hadd2(a1, c1);
    a2 = __hadd2(a2, c2); a3 = __hadd2(a3, c3);
    a0 = __hadd2(a0, shx_h2(a0, 8));
    a1 = __hadd2(a1, shx_h2(a1, 8));
    a2 = __hadd2(a2, shx_h2(a2, 8));
    a3 = __hadd2(a3, shx_h2(a3, 8));
    float2 f0 = __half22float2(a0), f1 = __half22float2(a1);
    float2 f2 = __half22float2(a2), f3 = __half22float2(a3);
    f[0] = f0.x; f[1] = f0.y; f[2] = f1.x; f[3] = f1.y;
    f[4] = f2.x; f[5] = f2.y; f[6] = f3.x; f[7] = f3.y;
}

// ---------------- fused gather(4 nodes/wave) + relu + LDS matmul (permuted W, k4-outer) ----------------
__global__ __launch_bounds__(256) void k_gmm(
        const int* __restrict__ rowptr, const int* __restrict__ col,
        const float* __restrict__ dinv, const float* __restrict__ b,
        const __half* __restrict__ hw_in, const float* __restrict__ W,
        __half* __restrict__ hw_out) {
    __shared__ float sW[64 * 64];
    __shared__ float sA[16 * 64];
    int t = threadIdx.x;
    stage_w_perm(W, sW, t);
    __syncthreads();

    int wave = t >> 6, lane = t & 63;
    int quarter = lane >> 4, slot = (lane >> 3) & 1, sub = lane & 7;
    int i0 = blockIdx.x * 16 + wave * 4;
    int i = i0 + quarter;
    float di = dinv[i];
    int rs = rowptr[i], re = rowptr[i + 1];
    const uint4* hv = (const uint4*)hw_in;

    float f[8];
    gather2x4(col, hv, rs, re, slot, sub, f);

    uint4 us = hv[(size_t)i * 8 + sub];
    float2 s0 = __half22float2(*(__half2*)&us.x);
    float2 s1 = __half22float2(*(__half2*)&us.y);
    float2 s2 = __half22float2(*(__half2*)&us.z);
    float2 s3 = __half22float2(*(__half2*)&us.w);
    float sf[8] = {s0.x, s0.y, s1.x, s1.y, s2.x, s2.y, s3.x, s3.y};
    float4 ba = ((const float4*)b)[sub * 2];
    float4 bb = ((const float4*)b)[sub * 2 + 1];
    float bf[8] = {ba.x, ba.y, ba.z, ba.w, bb.x, bb.y, bb.z, bb.w};
    if (slot == 0) {
        float r[8];
#pragma unroll
        for (int k = 0; k < 8; ++k) r[k] = fmaxf(fmaf(di, f[k] + sf[k], bf[k]), 0.f);
        *(float4*)&sA[(wave * 4 + quarter) * 64 + sub * 8]     = make_float4(r[0], r[1], r[2], r[3]);
        *(float4*)&sA[(wave * 4 + quarter) * 64 + sub * 8 + 4] = make_float4(r[4], r[5], r[6], r[7]);
    }
    // wave-local: sA rows for this wave are written by this wave's own lanes (no barrier needed)

    const float4* sWp = (const float4*)sW;     // [k4*64 + lane]
    float sum[4] = {0.f, 0.f, 0.f, 0.f};
#pragma unroll
    for (int k4 = 0; k4 < 16; ++k4) {
        float4 w4 = sWp[k4 * 64 + lane];       // read once per thread
#pragma unroll
        for (int hh = 0; hh < 4; ++hh) {
            float4 a4 = ((const float4*)&sA[(wave * 4 + hh) * 64])[k4];   // broadcast
            sum[hh] = fmaf(a4.x, w4.x, sum[hh]);
            sum[hh] = fmaf(a4.y, w4.y, sum[hh]);
            sum[hh] = fmaf(a4.z, w4.z, sum[hh]);
            sum[hh] = fmaf(a4.w, w4.w, sum[hh]);
        }
    }
#pragma unroll
    for (int hh = 0; hh < 4; ++hh)
        hw_out[(size_t)(i0 + hh) * 64 + lane] = __float2half_rn(sum[hh] * dinv[i0 + hh]);
}

// ---------------- layer-3 gather (4 nodes/wave; fp16 conv out) ----------------
__global__ __launch_bounds__(256) void k_gather3(
        const int* __restrict__ rowptr, const int* __restrict__ col,
        const float* __restrict__ dinv, const float* __restrict__ b,
        const __half* __restrict__ hw_in, __half* __restrict__ conv) {
    int t = threadIdx.x;
    int wave = t >> 6, lane = t & 63;
    int quarter = lane >> 4, slot = (lane >> 3) & 1, sub = lane & 7;
    int i = blockIdx.x * 16 + wave * 4 + quarter;
    float di = dinv[i];
    int rs = rowptr[i], re = rowptr[i + 1];
    const uint4* hv = (const uint4*)hw_in;

    float f[8];
    gather2x4(col, hv, rs, re, slot, sub, f);

    if (slot == 0) {
        uint4 us = hv[(size_t)i * 8 + sub];
        float2 s0 = __half22float2(*(__half2*)&us.x);
        float2 s1 = __half22float2(*(__half2*)&us.y);
        float2 s2 = __half22float2(*(__half2*)&us.z);
        float2 s3 = __half22float2(*(__half2*)&us.w);
        float sf[8] = {s0.x, s0.y, s1.x, s1.y, s2.x, s2.y, s3.x, s3.y};
        float4 ba = ((const float4*)b)[sub * 2];
        float4 bb = ((const float4*)b)[sub * 2 + 1];
        float bf[8] = {ba.x, ba.y, ba.z, ba.w, bb.x, bb.y, bb.z, bb.w};
        uint4 o;
        __half2* oh = (__half2*)&o;
#pragma unroll
        for (int c = 0; c < 4; ++c) {
            float r0 = fmaf(di, f[2 * c] + sf[2 * c], bf[2 * c]);
            float r1 = fmaf(di, f[2 * c + 1] + sf[2 * c + 1], bf[2 * c + 1]);
            oh[c] = __halves2half2(__float2half_rn(r0), __float2half_rn(r1));
        }
        ((uint4*)conv)[(size_t)i * 8 + sub] = o;
    }
}

// ---------------- fused mean-pool + dense + softmax + threshold: 1 graph/block ----------------
__global__ __launch_bounds__(256) void k_dense(
        const __half* __restrict__ conv, const int* __restrict__ gstart,
        const float* __restrict__ Wd, const float* __restrict__ bd,
        float* __restrict__ out) {
    __shared__ float sred[4][64];
    __shared__ float sp[64];
    __shared__ float rmax[4];
    __shared__ float rsum[4];
    int t = threadIdx.x;
    int wave = t >> 6, lane = t & 63;
    int g = blockIdx.x;
    int n0 = gstart[g], n1 = gstart[g + 1];

    // ---- mean pool over contiguous node range [n0, n1) ----
    int fp = lane & 31;            // feature pair index (2 feats per lane)
    int par = lane >> 5;           // which of the 2 nodes this half-wave reads
    const __half2* conv2 = (const __half2*)conv;
    float2 acc2 = make_float2(0.f, 0.f);
    for (int i = n0 + wave * 2 + par; i < n1; i += 8) {
        float2 f = __half22float2(conv2[(size_t)i * 32 + fp]);
        acc2.x += f.x; acc2.y += f.y;
    }
    acc2.x += __shfl_xor(acc2.x, 32);   // combine the two node-parities
    acc2.y += __shfl_xor(acc2.y, 32);
    if (lane < 32) { sred[wave][2 * fp] = acc2.x; sred[wave][2 * fp + 1] = acc2.y; }
    __syncthreads();
    if (t < 64) {
        int n = n1 - n0;
        float s = sred[0][t] + sred[1][t] + sred[2][t] + sred[3][t];
        sp[t] = (n > 0) ? s / (float)n : 0.f;
    }
    __syncthreads();

    // ---- dense: 2048 logits, 8 per thread ----
    float acc[8];
#pragma unroll
    for (int r = 0; r < 8; ++r) acc[r] = bd[r * 256 + t];
    for (int k = 0; k < 64; ++k) {
        float h = sp[k];
#pragma unroll
        for (int r = 0; r < 8; ++r)
            acc[r] = fmaf(h, Wd[k * BIOPRINT + r * 256 + t], acc[r]);
    }

    // ---- softmax over 2048 within the block ----
    float m = acc[0];
#pragma unroll
    for (int r = 1; r < 8; ++r) m = fmaxf(m, acc[r]);
#pragma unroll
    for (int off = 32; off > 0; off >>= 1) m = fmaxf(m, __shfl_xor(m, off));
    if (lane == 0) rmax[wave] = m;
    __syncthreads();
    m = fmaxf(fmaxf(rmax[0], rmax[1]), fmaxf(rmax[2], rmax[3]));

    float s = 0.f;
#pragma unroll
    for (int r = 0; r < 8; ++r) { acc[r] = expf(acc[r] - m); s += acc[r]; }
#pragma unroll
    for (int off = 32; off > 0; off >>= 1) s += __shfl_xor(s, off);
    if (lane == 0) rsum[wave] = s;
    __syncthreads();
    s = rsum[0] + rsum[1] + rsum[2] + rsum[3];

#pragma unroll
    for (int r = 0; r < 8; ++r) {
        float p = acc[r] / s;
        out[(size_t)g * BIOPRINT + r * 256 + t] = (p >= 0.5f) ? 1.0f : 0.0f;
    }
}

// ---------------- launch ----------------

extern "C" void kernel_launch(void* const* d_in, const int* in_sizes, int n_in,
                              void* d_out, int out_size, void* d_ws, size_t ws_size,
                              hipStream_t stream) {
    const float* x     = (const float*)d_in[0];
    const int*   ei    = (const int*)d_in[1];
    const int*   batch = (const int*)d_in[2];
    const float* W1 = (const float*)d_in[3];
    const float* b1 = (const float*)d_in[4];
    const float* W2 = (const float*)d_in[5];
    const float* b2 = (const float*)d_in[6];
    const float* W3 = (const float*)d_in[7];
    const float* b3 = (const float*)d_in[8];
    const float* Wd = (const float*)d_in[9];
    const float* bd = (const float*)d_in[10];
    float* out = (float*)d_out;

    const int* src = ei;
    const int* dst = ei + N_EDGES;

    char* ws = (char*)d_ws;
    size_t off = 0;
    auto alloc = [&](size_t bytes) {
        void* p = ws + off;
        off += (bytes + 255) & ~(size_t)255;
        return p;
    };
    int*    deg    = (int*)alloc(N_NODES * sizeof(int));
    float*  dinv   = (float*)alloc(N_NODES * sizeof(float));
    int*    rowptr = (int*)alloc((N_NODES + 1) * sizeof(int));
    int*    bsum   = (int*)alloc(128 * sizeof(int));
    int*    rank   = (int*)alloc((size_t)N_EDGES * sizeof(int));
    int*    gstart = (int*)alloc((N_GRAPHS + 1) * sizeof(int));
    int*    col    = (int*)alloc((size_t)COL_CAP * sizeof(int));
    __half* bufA   = (__half*)alloc((size_t)(N_NODES + 1) * HIDDEN * sizeof(__half));
    __half* bufB   = (__half*)alloc((size_t)(N_NODES + 1) * HIDDEN * sizeof(__half));
    __half* conv   = (__half*)alloc((size_t)N_NODES * HIDDEN * sizeof(__half));

    hipMemsetAsync(deg, 0, N_NODES * sizeof(int), stream);
    // zero sentinel feature rows (read by padded gathers; never written by mm kernels)
    hipMemsetAsync(bufA + (size_t)N_NODES * HIDDEN, 0, HIDDEN * sizeof(__half), stream);
    hipMemsetAsync(bufB + (size_t)N_NODES * HIDDEN, 0, HIDDEN * sizeof(__half), stream);

    k_deg<<<DEG_BLOCKS, 256, 0, stream>>>(dst, deg, rank);
    k_scan1<<<N_SCAN_BLOCKS, SCAN_BLK, 0, stream>>>(deg, rowptr, bsum, dinv, N_NODES);
    k_scan3<<<N_SCAN_BLOCKS + 2, SCAN_BLK, 0, stream>>>(rowptr, deg, bsum, col,
                                                        batch, gstart, N_NODES);
    // single-pass atomic-free fill + 32-row layer-1 matmul fused
    k_fillmm<<<FILL_BLOCKS + MM_GRID32, 256, 0, stream>>>(src, dst, rank, rowptr, col,
                                                          x, W1, dinv, bufA);

    const int g16_grid = N_NODES / 16;         // 6250 (16 nodes/block)
    k_gmm<<<g16_grid, 256, 0, stream>>>(rowptr, col, dinv, b1, bufA, W2, bufB);
    k_gmm<<<g16_grid, 256, 0, stream>>>(rowptr, col, dinv, b2, bufB, W3, bufA);
    k_gather3<<<g16_grid, 256, 0, stream>>>(rowptr, col, dinv, b3, bufA, conv);
    k_dense<<<N_GRAPHS, 256, 0, stream>>>(conv, gstart, Wd, bd, out);
}